// Round 2
// baseline (457.148 us; speedup 1.0000x reference)
//
#include <hip/hip_runtime.h>
#include <hip/hip_bf16.h>

// SpikingSelfAttention — round 1: fp32 in/out (reference dtypes), correctness-first.
// B=8, C=512, T=4, N=256, L=T*N=1024, H=8, d=64.
// Attention reassociated as o = q @ (k^T v)  (exact: binary spikes -> integer math).

#define NB 8
#define NC 512
#define NT 4
#define NN 256
#define NL 1024
#define NH 8
#define ND 64
#define BCL (NB*NC*NL)   // 4,194,304 elements per (B,C,L) buffer

// ---------------------------------------------------------------------------
// BN (eval mode) + multi-step LIF over T.
// Input x: f32 (B,C,T,N). Output: f32 spikes (B,C,L), l = t*N+n (same layout).
// One thread per (b,c,n); loops t (LIF recurrence is over t).
__global__ void k_bn_lif(const float* __restrict__ x,
                         const float* __restrict__ g,  const float* __restrict__ bta,
                         const float* __restrict__ mu, const float* __restrict__ var,
                         float* __restrict__ out) {
  int gid = blockIdx.x * 256 + threadIdx.x;        // B*C*N threads
  int n = gid & (NN - 1);
  int c = (gid >> 8) & (NC - 1);
  float inv = g[c] / sqrtf(var[c] + 1e-5f);
  float m  = mu[c];
  float be = bta[c];
  size_t base = (size_t)(gid >> 8) * NL + n;       // (b*C + c)*L + n
  float v = 0.f;
#pragma unroll
  for (int t = 0; t < NT; t++) {
    float y = (x[base + t * NN] - m) * inv + be;
    v = v + (y - v) / 1.5f;                        // decay_input=True, tau=1.5
    float s = 0.f;
    if (v - 1.0f >= 0.f) { s = 1.f; v = 0.f; }     // spike + hard reset
    out[base + t * NN] = s;
  }
}

// Same, but in-place on workspace buffer (post-GEMM BN+LIF).
__global__ void k_bn_lif_inplace(float* __restrict__ y,
                                 const float* __restrict__ g,  const float* __restrict__ bta,
                                 const float* __restrict__ mu, const float* __restrict__ var) {
  int gid = blockIdx.x * 256 + threadIdx.x;
  int n = gid & (NN - 1);
  int c = (gid >> 8) & (NC - 1);
  float inv = g[c] / sqrtf(var[c] + 1e-5f);
  float m  = mu[c];
  float be = bta[c];
  size_t base = (size_t)(gid >> 8) * NL + n;
  float v = 0.f;
#pragma unroll
  for (int t = 0; t < NT; t++) {
    float yy = (y[base + t * NN] - m) * inv + be;
    v = v + (yy - v) / 1.5f;
    float s = 0.f;
    if (v - 1.0f >= 0.f) { s = 1.f; v = 0.f; }
    y[base + t * NN] = s;
  }
}

// ---------------------------------------------------------------------------
// Batched GEMM: Y[b,o,l] = sum_c W[o,c] * S[b,c,l].  W f32 (C,C); S,Y f32 (B,C,L).
// 64x64 tile, TK=16, 256 threads, 4x4 microtile. fp32 accumulation.
__global__ void k_gemm(const float* __restrict__ W, const float* __restrict__ S,
                       float* __restrict__ Y) {
  __shared__ float sW[64][17];   // [o][c], +1 pad: conflict-free col reads
  __shared__ float sS[16][64];   // [c][l]
  int b  = blockIdx.z;
  int o0 = blockIdx.y * 64, l0 = blockIdx.x * 64;
  int tid = threadIdx.x;
  int tx = tid & 15, ty = tid >> 4;
  const float* Sp = S + (size_t)b * NC * NL;
  float acc[4][4] = {};
  for (int kk = 0; kk < NC; kk += 16) {
#pragma unroll
    for (int r = 0; r < 4; r++) {
      int idx = tid + r * 256;
      int o = idx >> 4, c = idx & 15;
      sW[o][c] = W[(size_t)(o0 + o) * NC + kk + c];
    }
#pragma unroll
    for (int r = 0; r < 4; r++) {
      int idx = tid + r * 256;
      int c = idx >> 6, l = idx & 63;
      sS[c][l] = Sp[(size_t)(kk + c) * NL + l0 + l];
    }
    __syncthreads();
#pragma unroll
    for (int k = 0; k < 16; k++) {
      float wv[4], sv[4];
#pragma unroll
      for (int i = 0; i < 4; i++) wv[i] = sW[ty * 4 + i][k];
#pragma unroll
      for (int j = 0; j < 4; j++) sv[j] = sS[k][tx * 4 + j];
#pragma unroll
      for (int i = 0; i < 4; i++)
#pragma unroll
        for (int j = 0; j < 4; j++)
          acc[i][j] += wv[i] * sv[j];
    }
    __syncthreads();
  }
  float* Yp = Y + (size_t)b * NC * NL;
#pragma unroll
  for (int i = 0; i < 4; i++) {
    float4 v4 = make_float4(acc[i][0], acc[i][1], acc[i][2], acc[i][3]);
    *(float4*)&Yp[(size_t)(o0 + ty * 4 + i) * NL + l0 + tx * 4] = v4;
  }
}

// Final projection: same GEMM + bias, f32 output straight to d_out.
__global__ void k_gemm_bias(const float* __restrict__ W, const float* __restrict__ S,
                            const float* __restrict__ bias, float* __restrict__ Y) {
  __shared__ float sW[64][17];
  __shared__ float sS[16][64];
  int b  = blockIdx.z;
  int o0 = blockIdx.y * 64, l0 = blockIdx.x * 64;
  int tid = threadIdx.x;
  int tx = tid & 15, ty = tid >> 4;
  const float* Sp = S + (size_t)b * NC * NL;
  float acc[4][4] = {};
  for (int kk = 0; kk < NC; kk += 16) {
#pragma unroll
    for (int r = 0; r < 4; r++) {
      int idx = tid + r * 256;
      int o = idx >> 4, c = idx & 15;
      sW[o][c] = W[(size_t)(o0 + o) * NC + kk + c];
    }
#pragma unroll
    for (int r = 0; r < 4; r++) {
      int idx = tid + r * 256;
      int c = idx >> 6, l = idx & 63;
      sS[c][l] = Sp[(size_t)(kk + c) * NL + l0 + l];
    }
    __syncthreads();
#pragma unroll
    for (int k = 0; k < 16; k++) {
      float wv[4], sv[4];
#pragma unroll
      for (int i = 0; i < 4; i++) wv[i] = sW[ty * 4 + i][k];
#pragma unroll
      for (int j = 0; j < 4; j++) sv[j] = sS[k][tx * 4 + j];
#pragma unroll
      for (int i = 0; i < 4; i++)
#pragma unroll
        for (int j = 0; j < 4; j++)
          acc[i][j] += wv[i] * sv[j];
    }
    __syncthreads();
  }
  float* Yp = Y + (size_t)b * NC * NL;
#pragma unroll
  for (int i = 0; i < 4; i++) {
    float bb = bias[o0 + ty * 4 + i];
    float4 v4 = make_float4(acc[i][0] + bb, acc[i][1] + bb, acc[i][2] + bb, acc[i][3] + bb);
    *(float4*)&Yp[(size_t)(o0 + ty * 4 + i) * NL + l0 + tx * 4] = v4;
  }
}

// ---------------------------------------------------------------------------
// M[b,h,e,dd] = sum_l K[b,h*64+e,l] * V[b,h*64+dd,l]   (64x64, K-dim = L = 1024)
__global__ void k_kvM(const float* __restrict__ Ks, const float* __restrict__ Vs,
                      float* __restrict__ M) {
  int bh = blockIdx.x;
  int b = bh >> 3, h = bh & 7;
  const float* Kp = Ks + ((size_t)b * NC + h * ND) * NL;
  const float* Vp = Vs + ((size_t)b * NC + h * ND) * NL;
  __shared__ float sK[64][65];   // [lc][e], +1 pad
  __shared__ float sV[64][65];   // [lc][dd]
  int tid = threadIdx.x;
  int tx = tid & 15, ty = tid >> 4;
  float acc[4][4] = {};
  for (int l0 = 0; l0 < NL; l0 += 64) {
#pragma unroll
    for (int r = 0; r < 16; r++) {
      int idx = tid + r * 256;             // 0..4095
      int e = idx >> 6, lc = idx & 63;
      sK[lc][e] = Kp[(size_t)e * NL + l0 + lc];
      sV[lc][e] = Vp[(size_t)e * NL + l0 + lc];
    }
    __syncthreads();
#pragma unroll 8
    for (int lc = 0; lc < 64; lc++) {
      float kv[4], vv2[4];
#pragma unroll
      for (int i = 0; i < 4; i++) kv[i]  = sK[lc][ty * 4 + i];
#pragma unroll
      for (int j = 0; j < 4; j++) vv2[j] = sV[lc][tx * 4 + j];
#pragma unroll
      for (int i = 0; i < 4; i++)
#pragma unroll
        for (int j = 0; j < 4; j++)
          acc[i][j] += kv[i] * vv2[j];
    }
    __syncthreads();
  }
  float* Mp = M + (size_t)bh * ND * ND;
#pragma unroll
  for (int i = 0; i < 4; i++) {
    float4 v4 = make_float4(acc[i][0], acc[i][1], acc[i][2], acc[i][3]);
    *(float4*)&Mp[(ty * 4 + i) * ND + tx * 4] = v4;   // M[e][dd]
  }
}

// O[b,h*64+dd,i] = sum_e M[b,h,e,dd] * Q[b,h*64+e,i];  spike = (O_int >= 12) (exact)
__global__ void k_attn_spike(const float* __restrict__ Qs, const float* __restrict__ M,
                             float* __restrict__ Sout) {
  int bh = blockIdx.y;
  int b = bh >> 3, h = bh & 7;
  int i0 = blockIdx.x * 64;
  const float* Qp = Qs + ((size_t)b * NC + h * ND) * NL;
  const float* Mp = M + (size_t)bh * ND * ND;
  __shared__ float sM[64][64];   // [e][dd]
  __shared__ float sQ[64][64];   // [e][i]
  int tid = threadIdx.x;
  int tx = tid & 15, ty = tid >> 4;
#pragma unroll
  for (int r = 0; r < 16; r++) {
    int idx = tid + r * 256;
    int e = idx >> 6, x2 = idx & 63;
    sM[e][x2] = Mp[e * ND + x2];
    sQ[e][x2] = Qp[(size_t)e * NL + i0 + x2];
  }
  __syncthreads();
  float acc[4][4] = {};
#pragma unroll 8
  for (int e = 0; e < 64; e++) {
    float mv[4], qv[4];
#pragma unroll
    for (int i = 0; i < 4; i++) mv[i] = sM[e][ty * 4 + i];   // dd
#pragma unroll
    for (int j = 0; j < 4; j++) qv[j] = sQ[e][tx * 4 + j];   // i
#pragma unroll
    for (int i = 0; i < 4; i++)
#pragma unroll
      for (int j = 0; j < 4; j++)
        acc[i][j] += mv[i] * qv[j];
  }
  float* Sp = Sout + ((size_t)b * NC + h * ND) * NL;
#pragma unroll
  for (int i = 0; i < 4; i++) {
    float4 v4;
    v4.x = (acc[i][0] >= 12.0f) ? 1.f : 0.f;
    v4.y = (acc[i][1] >= 12.0f) ? 1.f : 0.f;
    v4.z = (acc[i][2] >= 12.0f) ? 1.f : 0.f;
    v4.w = (acc[i][3] >= 12.0f) ? 1.f : 0.f;
    *(float4*)&Sp[(size_t)(ty * 4 + i) * NL + i0 + tx * 4] = v4;
  }
}

// ---------------------------------------------------------------------------
extern "C" void kernel_launch(void* const* d_in, const int* in_sizes, int n_in,
                              void* d_out, int out_size, void* d_ws, size_t ws_size,
                              hipStream_t stream) {
  (void)in_sizes; (void)n_in; (void)out_size; (void)ws_size;
  const float* x   = (const float*)d_in[0];
  const float* wq  = (const float*)d_in[1];
  const float* wk  = (const float*)d_in[2];
  const float* wv  = (const float*)d_in[3];
  const float* wp  = (const float*)d_in[4];
  const float* bp  = (const float*)d_in[5];
  const float* gq  = (const float*)d_in[6];
  const float* bq  = (const float*)d_in[7];
  const float* mq  = (const float*)d_in[8];
  const float* vq  = (const float*)d_in[9];
  const float* gk  = (const float*)d_in[10];
  const float* bk  = (const float*)d_in[11];
  const float* mk  = (const float*)d_in[12];
  const float* vk  = (const float*)d_in[13];
  const float* gv  = (const float*)d_in[14];
  const float* bv  = (const float*)d_in[15];
  const float* mv  = (const float*)d_in[16];
  const float* vvv = (const float*)d_in[17];
  const float* gp  = (const float*)d_in[18];
  const float* bpn = (const float*)d_in[19];
  const float* mp  = (const float*)d_in[20];
  const float* vp  = (const float*)d_in[21];

  // Workspace layout (all f32): s0 | qs | ks | vs | M   (~65 MB)
  float* s0 = (float*)d_ws;
  float* qs = s0 + BCL;
  float* ks = qs + BCL;
  float* vs = ks + BCL;
  float* Mw = vs + BCL;

  dim3 blk(256);
  dim3 gg(NL / 64, NC / 64, NB);

  k_bn_lif<<<NB * NC * NN / 256, blk, 0, stream>>>(x, gp, bpn, mp, vp, s0);

  k_gemm<<<gg, blk, 0, stream>>>(wq, s0, qs);
  k_gemm<<<gg, blk, 0, stream>>>(wk, s0, ks);
  k_gemm<<<gg, blk, 0, stream>>>(wv, s0, vs);

  k_bn_lif_inplace<<<NB * NC * NN / 256, blk, 0, stream>>>(qs, gq, bq, mq, vq);
  k_bn_lif_inplace<<<NB * NC * NN / 256, blk, 0, stream>>>(ks, gk, bk, mk, vk);
  k_bn_lif_inplace<<<NB * NC * NN / 256, blk, 0, stream>>>(vs, gv, bv, mv, vvv);

  k_kvM<<<NB * NH, blk, 0, stream>>>(ks, vs, Mw);
  k_attn_spike<<<dim3(NL / 64, NB * NH), blk, 0, stream>>>(qs, Mw, s0);

  k_gemm_bias<<<gg, blk, 0, stream>>>(wp, s0, bp, (float*)d_out);
}

// Round 3
// 286.419 us; speedup vs baseline: 1.5961x; 1.5961x over previous
//
#include <hip/hip_runtime.h>
#include <hip/hip_bf16.h>

// SpikingSelfAttention — round 2: MFMA GEMMs via exact 3-way bf16 weight split.
// B=8, C=512, T=4, N=256, L=1024, H=8, d=64.
// Spikes are binary -> exact in bf16; w = h1+h2+h3 (bf16) exactly; attention
// reassociated o = q @ (k^T v), all-integer, threshold O>=12 exact.

#define NB 8
#define NC 512
#define NT 4
#define NN 256
#define NL 1024
#define NH 8
#define ND 64
#define BCL (NB*NC*NL)

typedef __attribute__((ext_vector_type(8))) short  short8v;
typedef __attribute__((ext_vector_type(8))) unsigned short us8;
typedef __attribute__((ext_vector_type(4))) unsigned short us4;
typedef __attribute__((ext_vector_type(4))) float f32x4;

__device__ __forceinline__ float bu2f(unsigned short u) {
  return __uint_as_float(((unsigned)u) << 16);
}
__device__ __forceinline__ unsigned short f2bu(float f) {   // RNE f32->bf16
  unsigned b = __float_as_uint(f);
  return (unsigned short)((b + 0x7FFFu + ((b >> 16) & 1u)) >> 16);
}

// ---------------------------------------------------------------------------
// Split 4 weight matrices (fp32 512x512) into 3 bf16 planes each. Exact sum.
// H[p][j][o][k] ushort. One thread per (p,o,k8).
__global__ void k_split(const float* __restrict__ wq, const float* __restrict__ wk,
                        const float* __restrict__ wv, const float* __restrict__ wp,
                        unsigned short* __restrict__ H) {
  int g = blockIdx.x * 256 + threadIdx.x;        // 4*512*64 = 131072
  int p = g >> 15;
  int o = (g >> 6) & 511;
  int k8 = g & 63;
  const float* W = (p == 0) ? wq : (p == 1) ? wk : (p == 2) ? wv : wp;
  const float* src = W + (size_t)o * NC + k8 * 8;
  us8 a1, a2, a3;
#pragma unroll
  for (int i = 0; i < 8; i++) {
    float w = src[i];
    unsigned short u1 = f2bu(w);
    float r1 = w - bu2f(u1);
    unsigned short u2 = f2bu(r1);
    float r2 = r1 - bu2f(u2);
    unsigned short u3 = f2bu(r2);
    a1[i] = u1; a2[i] = u2; a3[i] = u3;
  }
  size_t base = ((size_t)(p * 3) * NC + o) * NC + k8 * 8;
  *(us8*)&H[base]                      = a1;
  *(us8*)&H[base + (size_t)NC * NC]    = a2;
  *(us8*)&H[base + (size_t)2 * NC * NC] = a3;
}

// ---------------------------------------------------------------------------
// proj_bn + proj_lif: x (B,C,T,N) f32 -> spikes ST0[b][l][c] bf16 (transposed).
// One thread per (b, c-block-of-8, n); loops t. Coalesced x reads over n.
__global__ void k_bn_lif_t(const float* __restrict__ x,
                           const float* __restrict__ g,  const float* __restrict__ bt,
                           const float* __restrict__ mu, const float* __restrict__ var,
                           unsigned short* __restrict__ ST0) {
  int b  = blockIdx.x >> 6;
  int c0 = (blockIdx.x & 63) * 8;
  int n  = threadIdx.x;
  unsigned short spk[NT][8];
#pragma unroll
  for (int i = 0; i < 8; i++) {
    int c = c0 + i;
    float inv = g[c] / sqrtf(var[c] + 1e-5f);
    float m = mu[c], be = bt[c];
    const float* xp = x + ((size_t)(b * NC + c)) * NL + n;  // t stride = NN
    float v = 0.f;
#pragma unroll
    for (int t = 0; t < NT; t++) {
      float y = (xp[t * NN] - m) * inv + be;
      v = v + (y - v) / 1.5f;
      unsigned short s = 0;
      if (v - 1.0f >= 0.f) { s = 0x3F80; v = 0.f; }
      spk[t][i] = s;
    }
  }
#pragma unroll
  for (int t = 0; t < NT; t++) {
    us8 pk;
#pragma unroll
    for (int i = 0; i < 8; i++) pk[i] = spk[t][i];
    *(us8*)&ST0[((size_t)b * NL + t * NN + n) * NC + c0] = pk;
  }
}

// ---------------------------------------------------------------------------
// Fused q/k/v projection: Y = sum_j Hj @ S  (MFMA), then BN + LIF in epilogue,
// spikes out in [b][l][c] bf16. 128x128 tile, BK=64, 16x16x32 bf16 MFMA.
// Column tile = 32 n x 4 t, ordered cc = (nn&15) + 16*(t + 4*(nn>>4)) so the
// LIF recurrence over t is in-lane across acc fragments.
__global__ void k_qkv(const unsigned short* __restrict__ H,
                      const unsigned short* __restrict__ ST0,
                      const float* __restrict__ gq, const float* __restrict__ bq,
                      const float* __restrict__ mq, const float* __restrict__ vq,
                      const float* __restrict__ gk, const float* __restrict__ bk,
                      const float* __restrict__ mk, const float* __restrict__ vk,
                      const float* __restrict__ gv, const float* __restrict__ bv,
                      const float* __restrict__ mv, const float* __restrict__ vv,
                      unsigned short* __restrict__ STq, unsigned short* __restrict__ STk,
                      unsigned short* __restrict__ STv) {
  __shared__ unsigned short sA[128][72];   // [o][k], 144 B rows: 16B-aligned, 2-way banks
  __shared__ unsigned short sB[128][72];   // [cc][k]
  int z = blockIdx.z;
  int p = z >> 3, b = z & 7;
  int n0 = blockIdx.x * 32;
  int rowbase = blockIdx.y * 128;
  int tid = threadIdx.x;
  int wave = tid >> 6, lane = tid & 63, quad = lane >> 4, l15 = lane & 15;

  const unsigned short* Hp = H + (size_t)p * 3 * NC * NC;
  const unsigned short* Sb = ST0 + (size_t)b * NL * NC;

  f32x4 acc[2][8];
#pragma unroll
  for (int ri = 0; ri < 2; ri++)
#pragma unroll
    for (int f = 0; f < 8; f++) acc[ri][f] = (f32x4){0.f, 0.f, 0.f, 0.f};

  for (int j = 0; j < 3; j++) {
    const unsigned short* Hj = Hp + (size_t)j * NC * NC;
    for (int k0 = 0; k0 < NC; k0 += 64) {
#pragma unroll
      for (int i = 0; i < 4; i++) {
        int idx = tid + i * 256;
        int r = idx >> 3, seg = idx & 7;
        *(short8v*)&sA[r][seg * 8] =
            *(const short8v*)&Hj[(size_t)(rowbase + r) * NC + k0 + seg * 8];
      }
#pragma unroll
      for (int i = 0; i < 4; i++) {
        int idx = tid + i * 256;
        int cc = idx >> 3, seg = idx & 7;
        int f = cc >> 4;
        int l = (f & 3) * NN + n0 + (cc & 15) + ((f >> 2) << 4);
        *(short8v*)&sB[cc][seg * 8] =
            *(const short8v*)&Sb[(size_t)l * NC + k0 + seg * 8];
      }
      __syncthreads();
#pragma unroll
      for (int ks = 0; ks < 2; ks++) {
        short8v a0 = *(short8v*)&sA[wave * 32 + l15][ks * 32 + quad * 8];
        short8v a1 = *(short8v*)&sA[wave * 32 + 16 + l15][ks * 32 + quad * 8];
#pragma unroll
        for (int f = 0; f < 8; f++) {
          short8v bf = *(short8v*)&sB[f * 16 + l15][ks * 32 + quad * 8];
          acc[0][f] = __builtin_amdgcn_mfma_f32_16x16x32_bf16(a0, bf, acc[0][f], 0, 0, 0);
          acc[1][f] = __builtin_amdgcn_mfma_f32_16x16x32_bf16(a1, bf, acc[1][f], 0, 0, 0);
        }
      }
      __syncthreads();
    }
  }

  // Epilogue: BN + LIF (over t, in-lane), write binary spikes bf16 to [b][l][c].
  const float *g, *bb, *mm, *vr;
  unsigned short* So;
  if (p == 0)      { g = gq; bb = bq; mm = mq; vr = vq; So = STq; }
  else if (p == 1) { g = gk; bb = bk; mm = mk; vr = vk; So = STk; }
  else             { g = gv; bb = bv; mm = mv; vr = vv; So = STv; }
  So += (size_t)b * NL * NC;

#pragma unroll
  for (int ri = 0; ri < 2; ri++) {
    int ob = rowbase + wave * 32 + ri * 16 + quad * 4;
    float av[4], mvv[4], bvv[4];
#pragma unroll
    for (int r = 0; r < 4; r++) {
      av[r]  = g[ob + r] / sqrtf(vr[ob + r] + 1e-5f);
      mvv[r] = mm[ob + r];
      bvv[r] = bb[ob + r];
    }
#pragma unroll
    for (int nn4 = 0; nn4 < 2; nn4++) {
      unsigned short sp[4][4];   // [t][r]
#pragma unroll
      for (int r = 0; r < 4; r++) {
        float vmem = 0.f;
#pragma unroll
        for (int t = 0; t < NT; t++) {
          int f = t + nn4 * 4;
          float y = (acc[ri][f][r] - mvv[r]) * av[r] + bvv[r];
          vmem = vmem + (y - vmem) / 1.5f;
          unsigned short s = 0;
          if (vmem - 1.0f >= 0.f) { s = 0x3F80; vmem = 0.f; }
          sp[t][r] = s;
        }
      }
      int nn = l15 + nn4 * 16;
#pragma unroll
      for (int t = 0; t < NT; t++) {
        int l = t * NN + n0 + nn;
        us4 pk;
#pragma unroll
        for (int r = 0; r < 4; r++) pk[r] = sp[t][r];
        *(us4*)&So[(size_t)l * NC + ob] = pk;
      }
    }
  }
}

// ---------------------------------------------------------------------------
// Partial Gram: Mpart[ch][bh][e][dd] = sum_{l in chunk of 256} K[l][e]*V[l][dd].
// Integer-exact. 256 blocks (bh x chunk).
__global__ void k_kvM(const unsigned short* __restrict__ STk,
                      const unsigned short* __restrict__ STv,
                      float* __restrict__ Mpart) {
  int bh = blockIdx.x, ch = blockIdx.y;
  int b = bh >> 3, h = bh & 7;
  const unsigned short* Kp = STk + (size_t)b * NL * NC + h * ND;
  const unsigned short* Vp = STv + (size_t)b * NL * NC + h * ND;
  __shared__ float sK[64][72];
  __shared__ float sV[64][72];
  int tid = threadIdx.x, tx = tid & 15, ty = tid >> 4;
  float acc[4][4] = {};
  for (int lt = 0; lt < 4; lt++) {
    int lb = ch * 256 + lt * 64;
#pragma unroll
    for (int i = 0; i < 2; i++) {
      int idx = tid + i * 256;
      int r = idx >> 3, seg = idx & 7;
      us8 kv = *(const us8*)&Kp[(size_t)(lb + r) * NC + seg * 8];
      us8 vv = *(const us8*)&Vp[(size_t)(lb + r) * NC + seg * 8];
      float4 ka = make_float4(bu2f(kv[0]), bu2f(kv[1]), bu2f(kv[2]), bu2f(kv[3]));
      float4 kb = make_float4(bu2f(kv[4]), bu2f(kv[5]), bu2f(kv[6]), bu2f(kv[7]));
      float4 va = make_float4(bu2f(vv[0]), bu2f(vv[1]), bu2f(vv[2]), bu2f(vv[3]));
      float4 vb = make_float4(bu2f(vv[4]), bu2f(vv[5]), bu2f(vv[6]), bu2f(vv[7]));
      *(float4*)&sK[r][seg * 8]     = ka;
      *(float4*)&sK[r][seg * 8 + 4] = kb;
      *(float4*)&sV[r][seg * 8]     = va;
      *(float4*)&sV[r][seg * 8 + 4] = vb;
    }
    __syncthreads();
#pragma unroll 8
    for (int lc = 0; lc < 64; lc++) {
      float kvx[4], vvx[4];
#pragma unroll
      for (int i = 0; i < 4; i++) kvx[i] = sK[lc][ty * 4 + i];
#pragma unroll
      for (int j2 = 0; j2 < 4; j2++) vvx[j2] = sV[lc][tx * 4 + j2];
#pragma unroll
      for (int i = 0; i < 4; i++)
#pragma unroll
        for (int j2 = 0; j2 < 4; j2++)
          acc[i][j2] += kvx[i] * vvx[j2];
    }
    __syncthreads();
  }
  float* Mp = Mpart + ((size_t)ch * 64 + bh) * 4096;
#pragma unroll
  for (int i = 0; i < 4; i++) {
    float4 v4 = make_float4(acc[i][0], acc[i][1], acc[i][2], acc[i][3]);
    *(float4*)&Mp[(ty * 4 + i) * ND + tx * 4] = v4;
  }
}

// ---------------------------------------------------------------------------
// O[l][dd] = sum_e Q[l][e] * M[e][dd]; spike = (O >= 12). Writes STs[b][l][c] bf16.
__global__ void k_attn(const unsigned short* __restrict__ STq,
                       const float* __restrict__ Mpart,
                       unsigned short* __restrict__ STs) {
  int lt = blockIdx.x, bh = blockIdx.y;
  int b = bh >> 3, h = bh & 7;
  __shared__ float sM[64][64];    // [e][dd]
  __shared__ float sQT[64][65];   // [e][li] transposed
  int tid = threadIdx.x, tx = tid & 15, ty = tid >> 4;
#pragma unroll
  for (int i = 0; i < 16; i++) {
    int idx = tid + i * 256;
    float s = 0.f;
#pragma unroll
    for (int ch = 0; ch < 4; ch++)
      s += Mpart[((size_t)ch * 64 + bh) * 4096 + idx];
    ((float*)sM)[idx] = s;
  }
  const unsigned short* Qp = STq + (size_t)b * NL * NC + h * ND;
#pragma unroll
  for (int i = 0; i < 2; i++) {
    int idx = tid + i * 256;
    int r = idx >> 3, seg = idx & 7;   // r = li
    us8 qv = *(const us8*)&Qp[(size_t)(lt * 64 + r) * NC + seg * 8];
#pragma unroll
    for (int e2 = 0; e2 < 8; e2++) sQT[seg * 8 + e2][r] = bu2f(qv[e2]);
  }
  __syncthreads();
  float acc[4][4] = {};
#pragma unroll 8
  for (int e = 0; e < 64; e++) {
    float q[4], m[4];
#pragma unroll
    for (int i = 0; i < 4; i++) q[i] = sQT[e][ty * 4 + i];
#pragma unroll
    for (int j2 = 0; j2 < 4; j2++) m[j2] = sM[e][tx * 4 + j2];
#pragma unroll
    for (int i = 0; i < 4; i++)
#pragma unroll
      for (int j2 = 0; j2 < 4; j2++)
        acc[i][j2] += q[i] * m[j2];
  }
  unsigned short* Sp = STs + (size_t)b * NL * NC + h * ND;
#pragma unroll
  for (int i = 0; i < 4; i++) {
    us4 pk;
#pragma unroll
    for (int j2 = 0; j2 < 4; j2++) pk[j2] = (acc[i][j2] >= 12.0f) ? 0x3F80 : 0;
    *(us4*)&Sp[(size_t)(lt * 64 + ty * 4 + i) * NC + tx * 4] = pk;
  }
}

// ---------------------------------------------------------------------------
// Final projection: out[b][o][l] = sum_j H[3,j] @ STs + bp. fp32 out.
__global__ void k_out(const unsigned short* __restrict__ H,
                      const unsigned short* __restrict__ STs,
                      const float* __restrict__ bp, float* __restrict__ out) {
  __shared__ unsigned short sA[128][72];
  __shared__ unsigned short sB[128][72];
  int b = blockIdx.z;
  int l0 = blockIdx.x * 128;
  int rowbase = blockIdx.y * 128;
  int tid = threadIdx.x;
  int wave = tid >> 6, lane = tid & 63, quad = lane >> 4, l15 = lane & 15;
  const unsigned short* Hp = H + (size_t)3 * 3 * NC * NC;   // p=3 planes
  const unsigned short* Sb = STs + (size_t)b * NL * NC;
  f32x4 acc[2][8];
#pragma unroll
  for (int ri = 0; ri < 2; ri++)
#pragma unroll
    for (int f = 0; f < 8; f++) acc[ri][f] = (f32x4){0.f, 0.f, 0.f, 0.f};
  for (int j = 0; j < 3; j++) {
    const unsigned short* Hj = Hp + (size_t)j * NC * NC;
    for (int k0 = 0; k0 < NC; k0 += 64) {
#pragma unroll
      for (int i = 0; i < 4; i++) {
        int idx = tid + i * 256;
        int r = idx >> 3, seg = idx & 7;
        *(short8v*)&sA[r][seg * 8] =
            *(const short8v*)&Hj[(size_t)(rowbase + r) * NC + k0 + seg * 8];
      }
#pragma unroll
      for (int i = 0; i < 4; i++) {
        int idx = tid + i * 256;
        int cc = idx >> 3, seg = idx & 7;
        *(short8v*)&sB[cc][seg * 8] =
            *(const short8v*)&Sb[(size_t)(l0 + cc) * NC + k0 + seg * 8];
      }
      __syncthreads();
#pragma unroll
      for (int ks = 0; ks < 2; ks++) {
        short8v a0 = *(short8v*)&sA[wave * 32 + l15][ks * 32 + quad * 8];
        short8v a1 = *(short8v*)&sA[wave * 32 + 16 + l15][ks * 32 + quad * 8];
#pragma unroll
        for (int f = 0; f < 8; f++) {
          short8v bf = *(short8v*)&sB[f * 16 + l15][ks * 32 + quad * 8];
          acc[0][f] = __builtin_amdgcn_mfma_f32_16x16x32_bf16(a0, bf, acc[0][f], 0, 0, 0);
          acc[1][f] = __builtin_amdgcn_mfma_f32_16x16x32_bf16(a1, bf, acc[1][f], 0, 0, 0);
        }
      }
      __syncthreads();
    }
  }
#pragma unroll
  for (int ri = 0; ri < 2; ri++) {
    int ob = rowbase + wave * 32 + ri * 16 + quad * 4;
#pragma unroll
    for (int f = 0; f < 8; f++) {
      int l = l0 + f * 16 + l15;
#pragma unroll
      for (int r = 0; r < 4; r++) {
        out[((size_t)(b * NC + ob + r)) * NL + l] = acc[ri][f][r] + bp[ob + r];
      }
    }
  }
}

// ---------------------------------------------------------------------------
extern "C" void kernel_launch(void* const* d_in, const int* in_sizes, int n_in,
                              void* d_out, int out_size, void* d_ws, size_t ws_size,
                              hipStream_t stream) {
  (void)in_sizes; (void)n_in; (void)out_size; (void)ws_size;
  const float* x   = (const float*)d_in[0];
  const float* wq  = (const float*)d_in[1];
  const float* wk  = (const float*)d_in[2];
  const float* wv  = (const float*)d_in[3];
  const float* wp  = (const float*)d_in[4];
  const float* bp  = (const float*)d_in[5];
  const float* gq  = (const float*)d_in[6];
  const float* bq  = (const float*)d_in[7];
  const float* mq  = (const float*)d_in[8];
  const float* vq  = (const float*)d_in[9];
  const float* gk  = (const float*)d_in[10];
  const float* bk  = (const float*)d_in[11];
  const float* mk  = (const float*)d_in[12];
  const float* vk  = (const float*)d_in[13];
  const float* gv  = (const float*)d_in[14];
  const float* bv  = (const float*)d_in[15];
  const float* mv  = (const float*)d_in[16];
  const float* vvv = (const float*)d_in[17];
  const float* gp  = (const float*)d_in[18];
  const float* bpn = (const float*)d_in[19];
  const float* mp  = (const float*)d_in[20];
  const float* vp  = (const float*)d_in[21];

  // Workspace: H (4*3*512*512 us) | ST0 | STq | STk | STv | STs (BCL us each) | Mpart
  unsigned short* H   = (unsigned short*)d_ws;
  unsigned short* ST0 = H + (size_t)4 * 3 * NC * NC;
  unsigned short* STq = ST0 + BCL;
  unsigned short* STk = STq + BCL;
  unsigned short* STv = STk + BCL;
  unsigned short* STs = STv + BCL;
  float* Mpart = (float*)(STs + BCL);

  dim3 blk(256);
  k_split<<<512, blk, 0, stream>>>(wq, wk, wv, wp, H);
  k_bn_lif_t<<<NB * (NC / 8), blk, 0, stream>>>(x, gp, bpn, mp, vp, ST0);
  k_qkv<<<dim3(8, 4, 24), blk, 0, stream>>>(H, ST0,
      gq, bq, mq, vq, gk, bk, mk, vk, gv, bv, mv, vvv, STq, STk, STv);
  k_kvM<<<dim3(64, 4), blk, 0, stream>>>(STk, STv, Mpart);
  k_attn<<<dim3(16, 64), blk, 0, stream>>>(STq, Mpart, STs);
  k_out<<<dim3(8, 4, 8), blk, 0, stream>>>(H, STs, bp, (float*)d_out);
}

// Round 4
// 237.086 us; speedup vs baseline: 1.9282x; 1.2081x over previous
//
#include <hip/hip_runtime.h>
#include <hip/hip_bf16.h>

// SpikingSelfAttention — round 3: XOR-swizzled LDS + 64x64 wave tiles.
// B=8, C=512, T=4, N=256, L=1024, H=8, d=64.
// Exact 3-way bf16 weight split; binary spikes; o = q @ (k^T v) integer-exact.

#define NB 8
#define NC 512
#define NT 4
#define NN 256
#define NL 1024
#define NH 8
#define ND 64
#define BCL (NB*NC*NL)

typedef __attribute__((ext_vector_type(8))) short  short8v;
typedef __attribute__((ext_vector_type(8))) unsigned short us8;
typedef __attribute__((ext_vector_type(4))) unsigned short us4;
typedef __attribute__((ext_vector_type(4))) float f32x4;

__device__ __forceinline__ float bu2f(unsigned short u) {
  return __uint_as_float(((unsigned)u) << 16);
}
__device__ __forceinline__ unsigned short f2bu(float f) {   // RNE f32->bf16
  unsigned b = __float_as_uint(f);
  return (unsigned short)((b + 0x7FFFu + ((b >> 16) & 1u)) >> 16);
}

// ---------------------------------------------------------------------------
__global__ void k_split(const float* __restrict__ wq, const float* __restrict__ wk,
                        const float* __restrict__ wv, const float* __restrict__ wp,
                        unsigned short* __restrict__ H) {
  int g = blockIdx.x * 256 + threadIdx.x;        // 4*512*64 = 131072
  int p = g >> 15;
  int o = (g >> 6) & 511;
  int k8 = g & 63;
  const float* W = (p == 0) ? wq : (p == 1) ? wk : (p == 2) ? wv : wp;
  const float* src = W + (size_t)o * NC + k8 * 8;
  us8 a1, a2, a3;
#pragma unroll
  for (int i = 0; i < 8; i++) {
    float w = src[i];
    unsigned short u1 = f2bu(w);
    float r1 = w - bu2f(u1);
    unsigned short u2 = f2bu(r1);
    float r2 = r1 - bu2f(u2);
    unsigned short u3 = f2bu(r2);
    a1[i] = u1; a2[i] = u2; a3[i] = u3;
  }
  size_t base = ((size_t)(p * 3) * NC + o) * NC + k8 * 8;
  *(us8*)&H[base]                       = a1;
  *(us8*)&H[base + (size_t)NC * NC]     = a2;
  *(us8*)&H[base + (size_t)2 * NC * NC] = a3;
}

// ---------------------------------------------------------------------------
// proj_bn + proj_lif: x (B,C,T,N) f32 -> spikes ST0[b][l][c] bf16.
__global__ void k_bn_lif_t(const float* __restrict__ x,
                           const float* __restrict__ g,  const float* __restrict__ bt,
                           const float* __restrict__ mu, const float* __restrict__ var,
                           unsigned short* __restrict__ ST0) {
  int b  = blockIdx.x >> 6;
  int c0 = (blockIdx.x & 63) * 8;
  int n  = threadIdx.x;
  unsigned short spk[NT][8];
#pragma unroll
  for (int i = 0; i < 8; i++) {
    int c = c0 + i;
    float inv = g[c] / sqrtf(var[c] + 1e-5f);
    float m = mu[c], be = bt[c];
    const float* xp = x + ((size_t)(b * NC + c)) * NL + n;
    float v = 0.f;
#pragma unroll
    for (int t = 0; t < NT; t++) {
      float y = (xp[t * NN] - m) * inv + be;
      v = v + (y - v) / 1.5f;
      unsigned short s = 0;
      if (v - 1.0f >= 0.f) { s = 0x3F80; v = 0.f; }
      spk[t][i] = s;
    }
  }
#pragma unroll
  for (int t = 0; t < NT; t++) {
    us8 pk;
#pragma unroll
    for (int i = 0; i < 8; i++) pk[i] = spk[t][i];
    *(us8*)&ST0[((size_t)b * NL + t * NN + n) * NC + c0] = pk;
  }
}

// ---------------------------------------------------------------------------
// Fused q/k/v projection, 128x128 tile, BK=64, 16x16x32 MFMA, 2x2 waves of
// 64x64. LDS rows 64 bf16, XOR-swizzled 16B chunks (phys = log ^ (row&7)).
// Column tile: cc = (n&15) + 16*t + 64*(n>>4); wave col-frag j == t (LIF in-lane).
__global__ void k_qkv(const unsigned short* __restrict__ H,
                      const unsigned short* __restrict__ ST0,
                      const float* __restrict__ gq, const float* __restrict__ bq,
                      const float* __restrict__ mq, const float* __restrict__ vq,
                      const float* __restrict__ gk, const float* __restrict__ bk,
                      const float* __restrict__ mk, const float* __restrict__ vk,
                      const float* __restrict__ gv, const float* __restrict__ bv,
                      const float* __restrict__ mv, const float* __restrict__ vv,
                      unsigned short* __restrict__ STq, unsigned short* __restrict__ STk,
                      unsigned short* __restrict__ STv) {
  __shared__ unsigned short sA[128 * 64];
  __shared__ unsigned short sB[128 * 64];
  int z = blockIdx.z;
  int p = z >> 3, b = z & 7;
  int n0 = blockIdx.x * 32;
  int rowbase = blockIdx.y * 128;
  int tid = threadIdx.x;
  int wave = tid >> 6, lane = tid & 63, quad = lane >> 4, l15 = lane & 15;
  int wr = wave >> 1, wc = wave & 1;

  const unsigned short* Hp = H + (size_t)p * 3 * NC * NC;
  const unsigned short* Sb = ST0 + (size_t)b * NL * NC;

  f32x4 acc[4][4];
#pragma unroll
  for (int ri = 0; ri < 4; ri++)
#pragma unroll
    for (int j = 0; j < 4; j++) acc[ri][j] = (f32x4){0.f, 0.f, 0.f, 0.f};

  // Precompute B staging source l per iteration (cc -> l mapping).
  for (int j = 0; j < 3; j++) {
    const unsigned short* Hj = Hp + (size_t)j * NC * NC;
    for (int k0 = 0; k0 < NC; k0 += 64) {
#pragma unroll
      for (int i = 0; i < 4; i++) {
        int idx = tid + i * 256;
        int r = idx >> 3, seg = idx & 7;
        *(short8v*)&sA[r * 64 + ((seg ^ (r & 7)) * 8)] =
            *(const short8v*)&Hj[(size_t)(rowbase + r) * NC + k0 + seg * 8];
      }
#pragma unroll
      for (int i = 0; i < 4; i++) {
        int idx = tid + i * 256;
        int cc = idx >> 3, seg = idx & 7;
        int t = (cc >> 4) & 3, nn = (cc & 15) + ((cc >> 6) << 4);
        int l = t * NN + n0 + nn;
        *(short8v*)&sB[cc * 64 + ((seg ^ (cc & 7)) * 8)] =
            *(const short8v*)&Sb[(size_t)l * NC + k0 + seg * 8];
      }
      __syncthreads();
#pragma unroll
      for (int ks = 0; ks < 2; ks++) {
        int chunk = ks * 4 + quad;
        short8v afr[4], bfr[4];
#pragma unroll
        for (int ri = 0; ri < 4; ri++) {
          int r = wr * 64 + ri * 16 + l15;
          afr[ri] = *(short8v*)&sA[r * 64 + ((chunk ^ (r & 7)) * 8)];
        }
#pragma unroll
        for (int jj = 0; jj < 4; jj++) {
          int r = wc * 64 + jj * 16 + l15;
          bfr[jj] = *(short8v*)&sB[r * 64 + ((chunk ^ (r & 7)) * 8)];
        }
#pragma unroll
        for (int ri = 0; ri < 4; ri++)
#pragma unroll
          for (int jj = 0; jj < 4; jj++)
            acc[ri][jj] = __builtin_amdgcn_mfma_f32_16x16x32_bf16(
                afr[ri], bfr[jj], acc[ri][jj], 0, 0, 0);
      }
      __syncthreads();
    }
  }

  // Epilogue: BN + LIF over t (= col-fragment index j), in-lane.
  const float *g, *bb, *mm, *vr;
  unsigned short* So;
  if (p == 0)      { g = gq; bb = bq; mm = mq; vr = vq; So = STq; }
  else if (p == 1) { g = gk; bb = bk; mm = mk; vr = vk; So = STk; }
  else             { g = gv; bb = bv; mm = mv; vr = vv; So = STv; }
  So += (size_t)b * NL * NC;

  int nn = n0 + wc * 16 + l15;
#pragma unroll
  for (int ri = 0; ri < 4; ri++) {
    int ob = rowbase + wr * 64 + ri * 16 + quad * 4;
    float av[4], mvv[4], bvv[4];
#pragma unroll
    for (int r = 0; r < 4; r++) {
      av[r]  = g[ob + r] / sqrtf(vr[ob + r] + 1e-5f);
      mvv[r] = mm[ob + r];
      bvv[r] = bb[ob + r];
    }
    unsigned short sp[4][4];   // [t][r]
#pragma unroll
    for (int r = 0; r < 4; r++) {
      float vmem = 0.f;
#pragma unroll
      for (int t = 0; t < NT; t++) {
        float y = (acc[ri][t][r] - mvv[r]) * av[r] + bvv[r];
        vmem = vmem + (y - vmem) / 1.5f;
        unsigned short s = 0;
        if (vmem - 1.0f >= 0.f) { s = 0x3F80; vmem = 0.f; }
        sp[t][r] = s;
      }
    }
#pragma unroll
    for (int t = 0; t < NT; t++) {
      us4 pk;
#pragma unroll
      for (int r = 0; r < 4; r++) pk[r] = sp[t][r];
      *(us4*)&So[(size_t)(t * NN + nn) * NC + ob] = pk;
    }
  }
}

// ---------------------------------------------------------------------------
// Partial Gram: Mpart[ch][bh][e][dd] = sum_{l in 256-chunk} K[l][e]*V[l][dd].
__global__ void k_kvM(const unsigned short* __restrict__ STk,
                      const unsigned short* __restrict__ STv,
                      float* __restrict__ Mpart) {
  int bh = blockIdx.x, ch = blockIdx.y;
  int b = bh >> 3, h = bh & 7;
  const unsigned short* Kp = STk + (size_t)b * NL * NC + h * ND;
  const unsigned short* Vp = STv + (size_t)b * NL * NC + h * ND;
  __shared__ float sK[64][72];
  __shared__ float sV[64][72];
  int tid = threadIdx.x, tx = tid & 15, ty = tid >> 4;
  float acc[4][4] = {};
  for (int lt = 0; lt < 4; lt++) {
    int lb = ch * 256 + lt * 64;
#pragma unroll
    for (int i = 0; i < 2; i++) {
      int idx = tid + i * 256;
      int r = idx >> 3, seg = idx & 7;
      us8 kv = *(const us8*)&Kp[(size_t)(lb + r) * NC + seg * 8];
      us8 vv = *(const us8*)&Vp[(size_t)(lb + r) * NC + seg * 8];
#pragma unroll
      for (int q2 = 0; q2 < 8; q2++) {
        sK[r][seg * 8 + q2] = bu2f(kv[q2]);
        sV[r][seg * 8 + q2] = bu2f(vv[q2]);
      }
    }
    __syncthreads();
#pragma unroll 8
    for (int lc = 0; lc < 64; lc++) {
      float kvx[4], vvx[4];
#pragma unroll
      for (int i = 0; i < 4; i++) kvx[i] = sK[lc][ty * 4 + i];
#pragma unroll
      for (int j2 = 0; j2 < 4; j2++) vvx[j2] = sV[lc][tx * 4 + j2];
#pragma unroll
      for (int i = 0; i < 4; i++)
#pragma unroll
        for (int j2 = 0; j2 < 4; j2++)
          acc[i][j2] += kvx[i] * vvx[j2];
    }
    __syncthreads();
  }
  float* Mp = Mpart + ((size_t)ch * 64 + bh) * 4096;
#pragma unroll
  for (int i = 0; i < 4; i++) {
    float4 v4 = make_float4(acc[i][0], acc[i][1], acc[i][2], acc[i][3]);
    *(float4*)&Mp[(ty * 4 + i) * ND + tx * 4] = v4;
  }
}

// ---------------------------------------------------------------------------
// O[l][dd] = sum_e Q[l][e]*M[e][dd]; spike = (O >= 12). STs[b][l][c] bf16.
__global__ void k_attn(const unsigned short* __restrict__ STq,
                       const float* __restrict__ Mpart,
                       unsigned short* __restrict__ STs) {
  int lt = blockIdx.x, bh = blockIdx.y;
  int b = bh >> 3, h = bh & 7;
  __shared__ float sM[64][64];
  __shared__ float sQT[64][65];
  int tid = threadIdx.x, tx = tid & 15, ty = tid >> 4;
#pragma unroll
  for (int i = 0; i < 16; i++) {
    int idx = tid + i * 256;
    float s = 0.f;
#pragma unroll
    for (int ch = 0; ch < 4; ch++)
      s += Mpart[((size_t)ch * 64 + bh) * 4096 + idx];
    ((float*)sM)[idx] = s;
  }
  const unsigned short* Qp = STq + (size_t)b * NL * NC + h * ND;
#pragma unroll
  for (int i = 0; i < 2; i++) {
    int idx = tid + i * 256;
    int r = idx >> 3, seg = idx & 7;
    us8 qv = *(const us8*)&Qp[(size_t)(lt * 64 + r) * NC + seg * 8];
#pragma unroll
    for (int e2 = 0; e2 < 8; e2++) sQT[seg * 8 + e2][r] = bu2f(qv[e2]);
  }
  __syncthreads();
  float acc[4][4] = {};
#pragma unroll 8
  for (int e = 0; e < 64; e++) {
    float q[4], m[4];
#pragma unroll
    for (int i = 0; i < 4; i++) q[i] = sQT[e][ty * 4 + i];
#pragma unroll
    for (int j2 = 0; j2 < 4; j2++) m[j2] = sM[e][tx * 4 + j2];
#pragma unroll
    for (int i = 0; i < 4; i++)
#pragma unroll
      for (int j2 = 0; j2 < 4; j2++)
        acc[i][j2] += q[i] * m[j2];
  }
  unsigned short* Sp = STs + (size_t)b * NL * NC + h * ND;
#pragma unroll
  for (int i = 0; i < 4; i++) {
    us4 pk;
#pragma unroll
    for (int j2 = 0; j2 < 4; j2++) pk[j2] = (acc[i][j2] >= 12.0f) ? 0x3F80 : 0;
    *(us4*)&Sp[(size_t)(lt * 64 + ty * 4 + i) * NC + tx * 4] = pk;
  }
}

// ---------------------------------------------------------------------------
// Final projection: out[b][o][l] = sum_j H[3,j] @ STs + bp. Same MFMA structure.
__global__ void k_out(const unsigned short* __restrict__ H,
                      const unsigned short* __restrict__ STs,
                      const float* __restrict__ bp, float* __restrict__ out) {
  __shared__ unsigned short sA[128 * 64];
  __shared__ unsigned short sB[128 * 64];
  int b = blockIdx.z;
  int l0 = blockIdx.x * 128;
  int rowbase = blockIdx.y * 128;
  int tid = threadIdx.x;
  int wave = tid >> 6, lane = tid & 63, quad = lane >> 4, l15 = lane & 15;
  int wr = wave >> 1, wc = wave & 1;
  const unsigned short* Hp = H + (size_t)3 * 3 * NC * NC;
  const unsigned short* Sb = STs + (size_t)b * NL * NC;
  f32x4 acc[4][4];
#pragma unroll
  for (int ri = 0; ri < 4; ri++)
#pragma unroll
    for (int j = 0; j < 4; j++) acc[ri][j] = (f32x4){0.f, 0.f, 0.f, 0.f};
  for (int j = 0; j < 3; j++) {
    const unsigned short* Hj = Hp + (size_t)j * NC * NC;
    for (int k0 = 0; k0 < NC; k0 += 64) {
#pragma unroll
      for (int i = 0; i < 4; i++) {
        int idx = tid + i * 256;
        int r = idx >> 3, seg = idx & 7;
        *(short8v*)&sA[r * 64 + ((seg ^ (r & 7)) * 8)] =
            *(const short8v*)&Hj[(size_t)(rowbase + r) * NC + k0 + seg * 8];
      }
#pragma unroll
      for (int i = 0; i < 4; i++) {
        int idx = tid + i * 256;
        int cc = idx >> 3, seg = idx & 7;
        *(short8v*)&sB[cc * 64 + ((seg ^ (cc & 7)) * 8)] =
            *(const short8v*)&Sb[(size_t)(l0 + cc) * NC + k0 + seg * 8];
      }
      __syncthreads();
#pragma unroll
      for (int ks = 0; ks < 2; ks++) {
        int chunk = ks * 4 + quad;
        short8v afr[4], bfr[4];
#pragma unroll
        for (int ri = 0; ri < 4; ri++) {
          int r = wr * 64 + ri * 16 + l15;
          afr[ri] = *(short8v*)&sA[r * 64 + ((chunk ^ (r & 7)) * 8)];
        }
#pragma unroll
        for (int jj = 0; jj < 4; jj++) {
          int r = wc * 64 + jj * 16 + l15;
          bfr[jj] = *(short8v*)&sB[r * 64 + ((chunk ^ (r & 7)) * 8)];
        }
#pragma unroll
        for (int ri = 0; ri < 4; ri++)
#pragma unroll
          for (int jj = 0; jj < 4; jj++)
            acc[ri][jj] = __builtin_amdgcn_mfma_f32_16x16x32_bf16(
                afr[ri], bfr[jj], acc[ri][jj], 0, 0, 0);
      }
      __syncthreads();
    }
  }
#pragma unroll
  for (int ri = 0; ri < 4; ri++) {
    int ob = rowbase + wr * 64 + ri * 16 + quad * 4;
#pragma unroll
    for (int jj = 0; jj < 4; jj++) {
      int l = l0 + wc * 64 + jj * 16 + l15;
#pragma unroll
      for (int r = 0; r < 4; r++)
        out[((size_t)(b * NC + ob + r)) * NL + l] = acc[ri][jj][r] + bp[ob + r];
    }
  }
}

// ---------------------------------------------------------------------------
extern "C" void kernel_launch(void* const* d_in, const int* in_sizes, int n_in,
                              void* d_out, int out_size, void* d_ws, size_t ws_size,
                              hipStream_t stream) {
  (void)in_sizes; (void)n_in; (void)out_size; (void)ws_size;
  const float* x   = (const float*)d_in[0];
  const float* wq  = (const float*)d_in[1];
  const float* wk  = (const float*)d_in[2];
  const float* wv  = (const float*)d_in[3];
  const float* wp  = (const float*)d_in[4];
  const float* bp  = (const float*)d_in[5];
  const float* gq  = (const float*)d_in[6];
  const float* bq  = (const float*)d_in[7];
  const float* mq  = (const float*)d_in[8];
  const float* vq  = (const float*)d_in[9];
  const float* gk  = (const float*)d_in[10];
  const float* bk  = (const float*)d_in[11];
  const float* mk  = (const float*)d_in[12];
  const float* vk  = (const float*)d_in[13];
  const float* gv  = (const float*)d_in[14];
  const float* bv  = (const float*)d_in[15];
  const float* mv  = (const float*)d_in[16];
  const float* vvv = (const float*)d_in[17];
  const float* gp  = (const float*)d_in[18];
  const float* bpn = (const float*)d_in[19];
  const float* mp  = (const float*)d_in[20];
  const float* vp  = (const float*)d_in[21];

  unsigned short* H   = (unsigned short*)d_ws;
  unsigned short* ST0 = H + (size_t)4 * 3 * NC * NC;
  unsigned short* STq = ST0 + BCL;
  unsigned short* STk = STq + BCL;
  unsigned short* STv = STk + BCL;
  unsigned short* STs = STv + BCL;
  float* Mpart = (float*)(STs + BCL);

  dim3 blk(256);
  k_split<<<512, blk, 0, stream>>>(wq, wk, wv, wp, H);
  k_bn_lif_t<<<NB * (NC / 8), blk, 0, stream>>>(x, gp, bpn, mp, vp, ST0);
  k_qkv<<<dim3(8, 4, 24), blk, 0, stream>>>(H, ST0,
      gq, bq, mq, vq, gk, bk, mk, vk, gv, bv, mv, vvv, STq, STk, STv);
  k_kvM<<<dim3(64, 4), blk, 0, stream>>>(STk, STv, Mpart);
  k_attn<<<dim3(16, 64), blk, 0, stream>>>(STq, Mpart, STs);
  k_out<<<dim3(8, 4, 8), blk, 0, stream>>>(H, STs, bp, (float*)d_out);
}

// Round 5
// 227.560 us; speedup vs baseline: 2.0089x; 1.0419x over previous
//
#include <hip/hip_runtime.h>
#include <hip/hip_bf16.h>

// SpikingSelfAttention — round 5: global_load_lds staging + A-prefetch dbuf,
// B-tile hoisted out of plane loop, XCD-aware block swizzle.
// B=8, C=512, T=4, N=256, L=1024, H=8, d=64.
// Exact 3-way bf16 weight split; binary spikes; o = q @ (k^T v) integer-exact.

#define NB 8
#define NC 512
#define NT 4
#define NN 256
#define NL 1024
#define NH 8
#define ND 64
#define BCL (NB*NC*NL)

typedef __attribute__((ext_vector_type(8))) short  short8v;
typedef __attribute__((ext_vector_type(8))) unsigned short us8;
typedef __attribute__((ext_vector_type(4))) unsigned short us4;
typedef __attribute__((ext_vector_type(4))) float f32x4;

__device__ __forceinline__ float bu2f(unsigned short u) {
  return __uint_as_float(((unsigned)u) << 16);
}
__device__ __forceinline__ unsigned short f2bu(float f) {   // RNE f32->bf16
  unsigned b = __float_as_uint(f);
  return (unsigned short)((b + 0x7FFFu + ((b >> 16) & 1u)) >> 16);
}

// Async global->LDS, 16 B per lane. LDS dest = wave-uniform base + lane*16.
__device__ __forceinline__ void gld16(const unsigned short* g, unsigned short* l) {
  __builtin_amdgcn_global_load_lds(
      (const __attribute__((address_space(1))) unsigned int*)g,
      (__attribute__((address_space(3))) unsigned int*)l, 16, 0, 0);
}

// ---------------------------------------------------------------------------
__global__ void k_split(const float* __restrict__ wq, const float* __restrict__ wk,
                        const float* __restrict__ wv, const float* __restrict__ wp,
                        unsigned short* __restrict__ H) {
  int g = blockIdx.x * 256 + threadIdx.x;        // 4*512*64 = 131072
  int p = g >> 15;
  int o = (g >> 6) & 511;
  int k8 = g & 63;
  const float* W = (p == 0) ? wq : (p == 1) ? wk : (p == 2) ? wv : wp;
  const float* src = W + (size_t)o * NC + k8 * 8;
  us8 a1, a2, a3;
#pragma unroll
  for (int i = 0; i < 8; i++) {
    float w = src[i];
    unsigned short u1 = f2bu(w);
    float r1 = w - bu2f(u1);
    unsigned short u2 = f2bu(r1);
    float r2 = r1 - bu2f(u2);
    unsigned short u3 = f2bu(r2);
    a1[i] = u1; a2[i] = u2; a3[i] = u3;
  }
  size_t base = ((size_t)(p * 3) * NC + o) * NC + k8 * 8;
  *(us8*)&H[base]                       = a1;
  *(us8*)&H[base + (size_t)NC * NC]     = a2;
  *(us8*)&H[base + (size_t)2 * NC * NC] = a3;
}

// ---------------------------------------------------------------------------
// proj_bn + proj_lif: x (B,C,T,N) f32 -> spikes ST0[b][l][c] bf16.
__global__ void k_bn_lif_t(const float* __restrict__ x,
                           const float* __restrict__ g,  const float* __restrict__ bt,
                           const float* __restrict__ mu, const float* __restrict__ var,
                           unsigned short* __restrict__ ST0) {
  int b  = blockIdx.x >> 6;
  int c0 = (blockIdx.x & 63) * 8;
  int n  = threadIdx.x;
  unsigned short spk[NT][8];
#pragma unroll
  for (int i = 0; i < 8; i++) {
    int c = c0 + i;
    float inv = g[c] / sqrtf(var[c] + 1e-5f);
    float m = mu[c], be = bt[c];
    const float* xp = x + ((size_t)(b * NC + c)) * NL + n;
    float v = 0.f;
#pragma unroll
    for (int t = 0; t < NT; t++) {
      float y = (xp[t * NN] - m) * inv + be;
      v = v + (y - v) / 1.5f;
      unsigned short s = 0;
      if (v - 1.0f >= 0.f) { s = 0x3F80; v = 0.f; }
      spk[t][i] = s;
    }
  }
#pragma unroll
  for (int t = 0; t < NT; t++) {
    us8 pk;
#pragma unroll
    for (int i = 0; i < 8; i++) pk[i] = spk[t][i];
    *(us8*)&ST0[((size_t)b * NL + t * NN + n) * NC + c0] = pk;
  }
}

// ---------------------------------------------------------------------------
// Shared MFMA helpers (128x128 tile, BK=64, 2x2 waves of 64x64, XOR swizzle).
__device__ __forceinline__ void mfma_step(const unsigned short* __restrict__ bufA,
                                          const unsigned short* __restrict__ bufB,
                                          f32x4 acc[4][4], int wr, int wc,
                                          int quad, int l15) {
#pragma unroll
  for (int ks = 0; ks < 2; ks++) {
    int chunk = ks * 4 + quad;
    short8v afr[4], bfr[4];
#pragma unroll
    for (int ri = 0; ri < 4; ri++) {
      int r = wr * 64 + ri * 16 + l15;
      afr[ri] = *(const short8v*)&bufA[r * 64 + ((chunk ^ (r & 7)) << 3)];
    }
#pragma unroll
    for (int jj = 0; jj < 4; jj++) {
      int r = wc * 64 + jj * 16 + l15;
      bfr[jj] = *(const short8v*)&bufB[r * 64 + ((chunk ^ (r & 7)) << 3)];
    }
#pragma unroll
    for (int ri = 0; ri < 4; ri++)
#pragma unroll
      for (int jj = 0; jj < 4; jj++)
        acc[ri][jj] = __builtin_amdgcn_mfma_f32_16x16x32_bf16(
            afr[ri], bfr[jj], acc[ri][jj], 0, 0, 0);
  }
}

// Stage 128x64 weight tile (src pre-offset to rowbase) into LDS via DMA.
// Source-side XOR swizzle: lane seg fetches logical chunk seg^(r&7); LDS linear.
__device__ __forceinline__ void stage_w(const unsigned short* __restrict__ src,
                                        unsigned short* __restrict__ dst,
                                        int k0, int wave, int lane) {
  int seg = lane & 7;
  int rw = (wave << 5) + (lane >> 3);
#pragma unroll
  for (int c2 = 0; c2 < 4; c2++) {
    int r = rw + c2 * 8;
    gld16(&src[(size_t)r * NC + k0 + ((seg ^ (r & 7)) << 3)],
          &dst[((wave << 5) + c2 * 8) * 64]);
  }
}

// Stage 128-column spike tile for k_qkv: cc = (n&15) + 16*t + 64*(n>>4).
__device__ __forceinline__ void stage_sp(const unsigned short* __restrict__ Sb,
                                         unsigned short* __restrict__ dst,
                                         int k0, int n0, int wave, int lane) {
  int seg = lane & 7;
#pragma unroll
  for (int c2 = 0; c2 < 4; c2++) {
    int cc = (wave << 5) + c2 * 8 + (lane >> 3);
    int t = (cc >> 4) & 3, nn = (cc & 15) + ((cc >> 6) << 4);
    int l = t * NN + n0 + nn;
    gld16(&Sb[(size_t)l * NC + k0 + ((seg ^ (cc & 7)) << 3)],
          &dst[((wave << 5) + c2 * 8) * 64]);
  }
}

// Stage 128-column spike tile for k_out: l = l0 + cc (linear).
__device__ __forceinline__ void stage_sl(const unsigned short* __restrict__ Sb,
                                         unsigned short* __restrict__ dst,
                                         int k0, int l0, int wave, int lane) {
  int seg = lane & 7;
#pragma unroll
  for (int c2 = 0; c2 < 4; c2++) {
    int cc = (wave << 5) + c2 * 8 + (lane >> 3);
    gld16(&Sb[(size_t)(l0 + cc) * NC + k0 + ((seg ^ (cc & 7)) << 3)],
          &dst[((wave << 5) + c2 * 8) * 64]);
  }
}

// ---------------------------------------------------------------------------
// Fused q/k/v projection + BN + LIF epilogue. 1D grid of 768, XCD-swizzled.
__global__ __launch_bounds__(256) void
k_qkv(const unsigned short* __restrict__ H,
      const unsigned short* __restrict__ ST0,
      const float* __restrict__ gq, const float* __restrict__ bq,
      const float* __restrict__ mq, const float* __restrict__ vq,
      const float* __restrict__ gk, const float* __restrict__ bk,
      const float* __restrict__ mk, const float* __restrict__ vk,
      const float* __restrict__ gv, const float* __restrict__ bv,
      const float* __restrict__ mv, const float* __restrict__ vv,
      unsigned short* __restrict__ STq, unsigned short* __restrict__ STk,
      unsigned short* __restrict__ STv) {
  __shared__ __align__(16) unsigned short sA0[128 * 64];
  __shared__ __align__(16) unsigned short sA1[128 * 64];
  __shared__ __align__(16) unsigned short sB[128 * 64];

  // XCD swizzle: blocks sharing an A-tile (p,rowbase) cluster on <=2 XCDs.
  int lid = blockIdx.x;                 // 0..767
  int xcd = lid & 7, slot = lid >> 3;   // slot 0..95
  int g2 = ((slot >> 5) << 3) | xcd;    // group 0..23 = p*8 + rbi*2 + bh2
  int within = slot & 31;
  int p = g2 >> 3;
  int rowbase = ((g2 >> 1) & 3) * 128;
  int b = ((g2 & 1) << 2) | (within >> 3);
  int n0 = (within & 7) * 32;

  int tid = threadIdx.x;
  int wave = tid >> 6, lane = tid & 63, quad = lane >> 4, l15 = lane & 15;
  int wr = wave >> 1, wc = wave & 1;

  const unsigned short* Hp = H + (size_t)p * 3 * NC * NC + (size_t)rowbase * NC;
  const unsigned short* Sb = ST0 + (size_t)b * NL * NC;

  f32x4 acc[4][4];
#pragma unroll
  for (int ri = 0; ri < 4; ri++)
#pragma unroll
    for (int j = 0; j < 4; j++) acc[ri][j] = (f32x4){0.f, 0.f, 0.f, 0.f};

  for (int k0i = 0; k0i < 8; k0i++) {
    int k0 = k0i * 64;
    stage_sp(Sb, sB, k0, n0, wave, lane);          // B once per k0
    stage_w(Hp, sA0, k0, wave, lane);              // plane 0
    __syncthreads();
    stage_w(Hp + NC * NC, sA1, k0, wave, lane);    // prefetch plane 1
    mfma_step(sA0, sB, acc, wr, wc, quad, l15);
    __syncthreads();
    stage_w(Hp + 2 * NC * NC, sA0, k0, wave, lane); // prefetch plane 2
    mfma_step(sA1, sB, acc, wr, wc, quad, l15);
    __syncthreads();
    mfma_step(sA0, sB, acc, wr, wc, quad, l15);
    __syncthreads();                               // protect sB/sA0 for next k0
  }

  // Epilogue: BN + LIF over t (= col-fragment index), in-lane.
  const float *g, *bb, *mm, *vr;
  unsigned short* So;
  if (p == 0)      { g = gq; bb = bq; mm = mq; vr = vq; So = STq; }
  else if (p == 1) { g = gk; bb = bk; mm = mk; vr = vk; So = STk; }
  else             { g = gv; bb = bv; mm = mv; vr = vv; So = STv; }
  So += (size_t)b * NL * NC;

  int nn = n0 + wc * 16 + l15;
#pragma unroll
  for (int ri = 0; ri < 4; ri++) {
    int ob = rowbase + wr * 64 + ri * 16 + quad * 4;
    float av[4], mvv[4], bvv[4];
#pragma unroll
    for (int r = 0; r < 4; r++) {
      av[r]  = g[ob + r] / sqrtf(vr[ob + r] + 1e-5f);
      mvv[r] = mm[ob + r];
      bvv[r] = bb[ob + r];
    }
    unsigned short sp[4][4];   // [t][r]
#pragma unroll
    for (int r = 0; r < 4; r++) {
      float vmem = 0.f;
#pragma unroll
      for (int t = 0; t < NT; t++) {
        float y = (acc[ri][t][r] - mvv[r]) * av[r] + bvv[r];
        vmem = vmem + (y - vmem) / 1.5f;
        unsigned short s = 0;
        if (vmem - 1.0f >= 0.f) { s = 0x3F80; vmem = 0.f; }
        sp[t][r] = s;
      }
    }
#pragma unroll
    for (int t = 0; t < NT; t++) {
      us4 pk;
#pragma unroll
      for (int r = 0; r < 4; r++) pk[r] = sp[t][r];
      *(us4*)&So[(size_t)(t * NN + nn) * NC + ob] = pk;
    }
  }
}

// ---------------------------------------------------------------------------
// Partial Gram: Mpart[ch][bh][e][dd] = sum_{l in 256-chunk} K[l][e]*V[l][dd].
__global__ void k_kvM(const unsigned short* __restrict__ STk,
                      const unsigned short* __restrict__ STv,
                      float* __restrict__ Mpart) {
  int bh = blockIdx.x, ch = blockIdx.y;
  int b = bh >> 3, h = bh & 7;
  const unsigned short* Kp = STk + (size_t)b * NL * NC + h * ND;
  const unsigned short* Vp = STv + (size_t)b * NL * NC + h * ND;
  __shared__ float sK[64][72];
  __shared__ float sV[64][72];
  int tid = threadIdx.x, tx = tid & 15, ty = tid >> 4;
  float acc[4][4] = {};
  for (int lt = 0; lt < 4; lt++) {
    int lb = ch * 256 + lt * 64;
#pragma unroll
    for (int i = 0; i < 2; i++) {
      int idx = tid + i * 256;
      int r = idx >> 3, seg = idx & 7;
      us8 kv = *(const us8*)&Kp[(size_t)(lb + r) * NC + seg * 8];
      us8 vv = *(const us8*)&Vp[(size_t)(lb + r) * NC + seg * 8];
#pragma unroll
      for (int q2 = 0; q2 < 8; q2++) {
        sK[r][seg * 8 + q2] = bu2f(kv[q2]);
        sV[r][seg * 8 + q2] = bu2f(vv[q2]);
      }
    }
    __syncthreads();
#pragma unroll 8
    for (int lc = 0; lc < 64; lc++) {
      float kvx[4], vvx[4];
#pragma unroll
      for (int i = 0; i < 4; i++) kvx[i] = sK[lc][ty * 4 + i];
#pragma unroll
      for (int j2 = 0; j2 < 4; j2++) vvx[j2] = sV[lc][tx * 4 + j2];
#pragma unroll
      for (int i = 0; i < 4; i++)
#pragma unroll
        for (int j2 = 0; j2 < 4; j2++)
          acc[i][j2] += kvx[i] * vvx[j2];
    }
    __syncthreads();
  }
  float* Mp = Mpart + ((size_t)ch * 64 + bh) * 4096;
#pragma unroll
  for (int i = 0; i < 4; i++) {
    float4 v4 = make_float4(acc[i][0], acc[i][1], acc[i][2], acc[i][3]);
    *(float4*)&Mp[(ty * 4 + i) * ND + tx * 4] = v4;
  }
}

// ---------------------------------------------------------------------------
// O[l][dd] = sum_e Q[l][e]*M[e][dd]; spike = (O >= 12). STs[b][l][c] bf16.
__global__ void k_attn(const unsigned short* __restrict__ STq,
                       const float* __restrict__ Mpart,
                       unsigned short* __restrict__ STs) {
  int lt = blockIdx.x, bh = blockIdx.y;
  int b = bh >> 3, h = bh & 7;
  __shared__ float sM[64][64];
  __shared__ float sQT[64][65];
  int tid = threadIdx.x, tx = tid & 15, ty = tid >> 4;
#pragma unroll
  for (int i = 0; i < 16; i++) {
    int idx = tid + i * 256;
    float s = 0.f;
#pragma unroll
    for (int ch = 0; ch < 4; ch++)
      s += Mpart[((size_t)ch * 64 + bh) * 4096 + idx];
    ((float*)sM)[idx] = s;
  }
  const unsigned short* Qp = STq + (size_t)b * NL * NC + h * ND;
#pragma unroll
  for (int i = 0; i < 2; i++) {
    int idx = tid + i * 256;
    int r = idx >> 3, seg = idx & 7;
    us8 qv = *(const us8*)&Qp[(size_t)(lt * 64 + r) * NC + seg * 8];
#pragma unroll
    for (int e2 = 0; e2 < 8; e2++) sQT[seg * 8 + e2][r] = bu2f(qv[e2]);
  }
  __syncthreads();
  float acc[4][4] = {};
#pragma unroll 8
  for (int e = 0; e < 64; e++) {
    float q[4], m[4];
#pragma unroll
    for (int i = 0; i < 4; i++) q[i] = sQT[e][ty * 4 + i];
#pragma unroll
    for (int j2 = 0; j2 < 4; j2++) m[j2] = sM[e][tx * 4 + j2];
#pragma unroll
    for (int i = 0; i < 4; i++)
#pragma unroll
      for (int j2 = 0; j2 < 4; j2++)
        acc[i][j2] += q[i] * m[j2];
  }
  unsigned short* Sp = STs + (size_t)b * NL * NC + h * ND;
#pragma unroll
  for (int i = 0; i < 4; i++) {
    us4 pk;
#pragma unroll
    for (int j2 = 0; j2 < 4; j2++) pk[j2] = (acc[i][j2] >= 12.0f) ? 0x3F80 : 0;
    *(us4*)&Sp[(size_t)(lt * 64 + ty * 4 + i) * NC + tx * 4] = pk;
  }
}

// ---------------------------------------------------------------------------
// Final projection: out[b][o][l] = sum_j H[3,j] @ STs + bp. 1D grid 256,
// XCD-swizzled, same DMA + prefetch pipeline as k_qkv.
__global__ __launch_bounds__(256) void
k_out(const unsigned short* __restrict__ H,
      const unsigned short* __restrict__ STs,
      const float* __restrict__ bp, float* __restrict__ out) {
  __shared__ __align__(16) unsigned short sA0[128 * 64];
  __shared__ __align__(16) unsigned short sA1[128 * 64];
  __shared__ __align__(16) unsigned short sB[128 * 64];

  int lid = blockIdx.x;                 // 0..255
  int xcd = lid & 7, slot = lid >> 3;   // slot 0..31
  int rowbase = (xcd >> 1) * 128;       // group = xcd: rbi = xcd>>1, bh2 = xcd&1
  int b = ((xcd & 1) << 2) | (slot >> 3);
  int l0 = (slot & 7) * 128;

  int tid = threadIdx.x;
  int wave = tid >> 6, lane = tid & 63, quad = lane >> 4, l15 = lane & 15;
  int wr = wave >> 1, wc = wave & 1;

  const unsigned short* Hp = H + (size_t)3 * 3 * NC * NC + (size_t)rowbase * NC;
  const unsigned short* Sb = STs + (size_t)b * NL * NC;

  f32x4 acc[4][4];
#pragma unroll
  for (int ri = 0; ri < 4; ri++)
#pragma unroll
    for (int j = 0; j < 4; j++) acc[ri][j] = (f32x4){0.f, 0.f, 0.f, 0.f};

  for (int k0i = 0; k0i < 8; k0i++) {
    int k0 = k0i * 64;
    stage_sl(Sb, sB, k0, l0, wave, lane);
    stage_w(Hp, sA0, k0, wave, lane);
    __syncthreads();
    stage_w(Hp + NC * NC, sA1, k0, wave, lane);
    mfma_step(sA0, sB, acc, wr, wc, quad, l15);
    __syncthreads();
    stage_w(Hp + 2 * NC * NC, sA0, k0, wave, lane);
    mfma_step(sA1, sB, acc, wr, wc, quad, l15);
    __syncthreads();
    mfma_step(sA0, sB, acc, wr, wc, quad, l15);
    __syncthreads();
  }

#pragma unroll
  for (int ri = 0; ri < 4; ri++) {
    int ob = rowbase + wr * 64 + ri * 16 + quad * 4;
#pragma unroll
    for (int jj = 0; jj < 4; jj++) {
      int l = l0 + wc * 64 + jj * 16 + l15;
#pragma unroll
      for (int r = 0; r < 4; r++)
        out[((size_t)(b * NC + ob + r)) * NL + l] = acc[ri][jj][r] + bp[ob + r];
    }
  }
}

// ---------------------------------------------------------------------------
extern "C" void kernel_launch(void* const* d_in, const int* in_sizes, int n_in,
                              void* d_out, int out_size, void* d_ws, size_t ws_size,
                              hipStream_t stream) {
  (void)in_sizes; (void)n_in; (void)out_size; (void)ws_size;
  const float* x   = (const float*)d_in[0];
  const float* wq  = (const float*)d_in[1];
  const float* wk  = (const float*)d_in[2];
  const float* wv  = (const float*)d_in[3];
  const float* wp  = (const float*)d_in[4];
  const float* bp  = (const float*)d_in[5];
  const float* gq  = (const float*)d_in[6];
  const float* bq  = (const float*)d_in[7];
  const float* mq  = (const float*)d_in[8];
  const float* vq  = (const float*)d_in[9];
  const float* gk  = (const float*)d_in[10];
  const float* bk  = (const float*)d_in[11];
  const float* mk  = (const float*)d_in[12];
  const float* vk  = (const float*)d_in[13];
  const float* gv  = (const float*)d_in[14];
  const float* bv  = (const float*)d_in[15];
  const float* mv  = (const float*)d_in[16];
  const float* vvv = (const float*)d_in[17];
  const float* gp  = (const float*)d_in[18];
  const float* bpn = (const float*)d_in[19];
  const float* mp  = (const float*)d_in[20];
  const float* vp  = (const float*)d_in[21];

  unsigned short* H   = (unsigned short*)d_ws;
  unsigned short* ST0 = H + (size_t)4 * 3 * NC * NC;
  unsigned short* STq = ST0 + BCL;
  unsigned short* STk = STq + BCL;
  unsigned short* STv = STk + BCL;
  unsigned short* STs = STv + BCL;
  float* Mpart = (float*)(STs + BCL);

  dim3 blk(256);
  k_split<<<512, blk, 0, stream>>>(wq, wk, wv, wp, H);
  k_bn_lif_t<<<NB * (NC / 8), blk, 0, stream>>>(x, gp, bpn, mp, vp, ST0);
  k_qkv<<<768, blk, 0, stream>>>(H, ST0,
      gq, bq, mq, vq, gk, bk, mk, vk, gv, bv, mv, vvv, STq, STk, STv);
  k_kvM<<<dim3(64, 4), blk, 0, stream>>>(STk, STv, Mpart);
  k_attn<<<dim3(16, 64), blk, 0, stream>>>(STq, Mpart, STs);
  k_out<<<256, blk, 0, stream>>>(H, STs, bp, (float*)d_out);
}

// Round 6
// 213.615 us; speedup vs baseline: 2.1401x; 1.0653x over previous
//
#include <hip/hip_runtime.h>
#include <hip/hip_bf16.h>

// SpikingSelfAttention — round 6: fragment-ordered weights (A direct from
// global/L2, no LDS for A), 1 barrier per k0, B-dbuf in LDS, 4x1 wave strips.
// B=8, C=512, T=4, N=256, L=1024, H=8, d=64.
// Exact 3-way bf16 weight split; binary spikes; o = q @ (k^T v) integer-exact.

#define NB 8
#define NC 512
#define NT 4
#define NN 256
#define NL 1024
#define NH 8
#define ND 64
#define BCL (NB*NC*NL)

typedef __attribute__((ext_vector_type(8))) short  short8v;
typedef __attribute__((ext_vector_type(8))) unsigned short us8;
typedef __attribute__((ext_vector_type(4))) unsigned short us4;
typedef __attribute__((ext_vector_type(4))) float f32x4;

__device__ __forceinline__ float bu2f(unsigned short u) {
  return __uint_as_float(((unsigned)u) << 16);
}
__device__ __forceinline__ unsigned short f2bu(float f) {   // RNE f32->bf16
  unsigned b = __float_as_uint(f);
  return (unsigned short)((b + 0x7FFFu + ((b >> 16) & 1u)) >> 16);
}

// ---------------------------------------------------------------------------
// k_prep: blocks [0,512) = weight split into fragment-ordered H2;
//         blocks [512,1024) = proj BN+LIF -> ST0[b][l][c] bf16.
// H2 layout: offset = ((((p*3+j)*4+rt)*8+k0i)*8+chunk)*1024 + r*8
//   (p: which W; j: plane; rt: 128-row tile; k0i: 64-k tile; chunk: 8-k; r: row)
__global__ void k_prep(const float* __restrict__ wq, const float* __restrict__ wk,
                       const float* __restrict__ wv, const float* __restrict__ wp,
                       const float* __restrict__ x,
                       const float* __restrict__ g,  const float* __restrict__ bt,
                       const float* __restrict__ mu, const float* __restrict__ var,
                       unsigned short* __restrict__ H2,
                       unsigned short* __restrict__ ST0) {
  if (blockIdx.x < 512) {
    int gi = blockIdx.x * 256 + threadIdx.x;       // (p,o,k8): 4*512*64
    int p = gi >> 15;
    int o = (gi >> 6) & 511;
    int k8 = gi & 63;
    int rt = o >> 7, r = o & 127;
    int k0i = k8 >> 3, chunk = k8 & 7;
    const float* W = (p == 0) ? wq : (p == 1) ? wk : (p == 2) ? wv : wp;
    const float* src = W + (size_t)o * NC + k8 * 8;
    us8 a[3];
#pragma unroll
    for (int i = 0; i < 8; i++) {
      float w = src[i];
      unsigned short u1 = f2bu(w);
      float r1 = w - bu2f(u1);
      unsigned short u2 = f2bu(r1);
      float r2 = r1 - bu2f(u2);
      unsigned short u3 = f2bu(r2);
      a[0][i] = u1; a[1][i] = u2; a[2][i] = u3;
    }
#pragma unroll
    for (int j = 0; j < 3; j++) {
      size_t off = ((size_t)((((p * 3 + j) * 4 + rt) * 8 + k0i) * 8 + chunk)) * 1024
                   + (size_t)r * 8;
      *(us8*)&H2[off] = a[j];
    }
  } else {
    int bidx = blockIdx.x - 512;
    int b  = bidx >> 6;
    int c0 = (bidx & 63) * 8;
    int n  = threadIdx.x;
    unsigned short spk[NT][8];
#pragma unroll
    for (int i = 0; i < 8; i++) {
      int c = c0 + i;
      float inv = g[c] / sqrtf(var[c] + 1e-5f);
      float m = mu[c], be = bt[c];
      const float* xp = x + ((size_t)(b * NC + c)) * NL + n;
      float v = 0.f;
#pragma unroll
      for (int t = 0; t < NT; t++) {
        float y = (xp[t * NN] - m) * inv + be;
        v = v + (y - v) / 1.5f;
        unsigned short s = 0;
        if (v - 1.0f >= 0.f) { s = 0x3F80; v = 0.f; }
        spk[t][i] = s;
      }
    }
#pragma unroll
    for (int t = 0; t < NT; t++) {
      us8 pk;
#pragma unroll
      for (int i = 0; i < 8; i++) pk[i] = spk[t][i];
      *(us8*)&ST0[((size_t)b * NL + t * NN + n) * NC + c0] = pk;
    }
  }
}

// ---------------------------------------------------------------------------
// Fused q/k/v projection + BN + LIF. Tile 128 rows x 128 cols; 4 waves as
// 4x1 strips (32 rows x 128 cols each). A fragments loaded directly from
// fragment-ordered H2 (global/L2). B (spikes) in LDS, dbuf, 1 barrier/k0.
// Column order: cc = (n&15) + 16*t + 64*(n>>4); LIF over t in-lane (jj&3).
__global__ __launch_bounds__(256) void
k_qkv(const unsigned short* __restrict__ H2,
      const unsigned short* __restrict__ ST0,
      const float* __restrict__ gq, const float* __restrict__ bq,
      const float* __restrict__ mq, const float* __restrict__ vq,
      const float* __restrict__ gk, const float* __restrict__ bk,
      const float* __restrict__ mk, const float* __restrict__ vk,
      const float* __restrict__ gv, const float* __restrict__ bv,
      const float* __restrict__ mv, const float* __restrict__ vv,
      unsigned short* __restrict__ STq, unsigned short* __restrict__ STk,
      unsigned short* __restrict__ STv) {
  __shared__ __align__(16) unsigned short sB[2][128 * 64];

  int id = blockIdx.x;                  // 768 = 8 n0 * 4 rt * 8 b * 3 p
  int n0 = (id & 7) * 32;
  int rt = (id >> 3) & 3;
  int b  = (id >> 5) & 7;
  int p  = id >> 8;

  int tid = threadIdx.x;
  int w = tid >> 6, lane = tid & 63, quad = lane >> 4, l15 = lane & 15;
  int xorv = l15 & 7;

  const unsigned short* Sb = ST0 + (size_t)b * NL * NC;

  f32x4 acc[2][8];
#pragma unroll
  for (int ri = 0; ri < 2; ri++)
#pragma unroll
    for (int jj = 0; jj < 8; jj++) acc[ri][jj] = (f32x4){0.f, 0.f, 0.f, 0.f};

  // B-tile load: thread i-th us8: cc = idx>>3, seg = idx&7.
  us8 breg[4];
  int ccs[4], segs[4];
  size_t bsrc[4];
#pragma unroll
  for (int i = 0; i < 4; i++) {
    int idx = tid + i * 256;
    int cc = idx >> 3, seg = idx & 7;
    int t = (cc >> 4) & 3, nn = (cc & 15) | ((cc >> 6) << 4);
    ccs[i] = cc; segs[i] = seg;
    bsrc[i] = (size_t)(t * NN + n0 + nn) * NC + seg * 8;
  }
#pragma unroll
  for (int i = 0; i < 4; i++) breg[i] = *(const us8*)&Sb[bsrc[i]];      // k0=0
#pragma unroll
  for (int i = 0; i < 4; i++)
    *(us8*)&sB[0][ccs[i] * 64 + ((segs[i] ^ (ccs[i] & 7)) << 3)] = breg[i];

  for (int k0i = 0; k0i < 8; k0i++) {
    __syncthreads();                    // sB[buf] ready; prior reads of buf^1 done
    int buf = k0i & 1;
    if (k0i < 7) {
#pragma unroll
      for (int i = 0; i < 4; i++)
        breg[i] = *(const us8*)&Sb[bsrc[i] + (size_t)(k0i + 1) * 64];
    }
#pragma unroll
    for (int j = 0; j < 3; j++) {
      const unsigned short* Hj =
          H2 + ((size_t)(((p * 3 + j) * 4 + rt) * 8 + k0i)) * 8192;
#pragma unroll
      for (int ks = 0; ks < 2; ks++) {
        int c8 = ks * 4 + quad;
        short8v a0 = *(const short8v*)&Hj[(size_t)c8 * 1024 + (w * 32 + l15) * 8];
        short8v a1 = *(const short8v*)&Hj[(size_t)c8 * 1024 + (w * 32 + 16 + l15) * 8];
        int poff = (c8 ^ xorv) << 3;
#pragma unroll
        for (int jj = 0; jj < 8; jj++) {
          short8v bf = *(const short8v*)&sB[buf][(jj * 16 + l15) * 64 + poff];
          acc[0][jj] = __builtin_amdgcn_mfma_f32_16x16x32_bf16(a0, bf, acc[0][jj], 0, 0, 0);
          acc[1][jj] = __builtin_amdgcn_mfma_f32_16x16x32_bf16(a1, bf, acc[1][jj], 0, 0, 0);
        }
      }
    }
    if (k0i < 7) {
#pragma unroll
      for (int i = 0; i < 4; i++)
        *(us8*)&sB[buf ^ 1][ccs[i] * 64 + ((segs[i] ^ (ccs[i] & 7)) << 3)] = breg[i];
    }
  }

  // Epilogue: BN + LIF over t (in-lane, jj = nhalf*4 + t).
  const float *g, *bb, *mm, *vr;
  unsigned short* So;
  if (p == 0)      { g = gq; bb = bq; mm = mq; vr = vq; So = STq; }
  else if (p == 1) { g = gk; bb = bk; mm = mk; vr = vk; So = STk; }
  else             { g = gv; bb = bv; mm = mv; vr = vv; So = STv; }
  So += (size_t)b * NL * NC;

#pragma unroll
  for (int ri = 0; ri < 2; ri++) {
    int ob = rt * 128 + w * 32 + ri * 16 + quad * 4;
    float av[4], mvv[4], bvv[4];
#pragma unroll
    for (int r = 0; r < 4; r++) {
      av[r]  = g[ob + r] / sqrtf(vr[ob + r] + 1e-5f);
      mvv[r] = mm[ob + r];
      bvv[r] = bb[ob + r];
    }
#pragma unroll
    for (int nh = 0; nh < 2; nh++) {
      int n = n0 + (nh << 4) + l15;
      unsigned short sp[4][4];          // [t][r]
#pragma unroll
      for (int r = 0; r < 4; r++) {
        float vmem = 0.f;
#pragma unroll
        for (int t = 0; t < NT; t++) {
          float y = (acc[ri][nh * 4 + t][r] - mvv[r]) * av[r] + bvv[r];
          vmem = vmem + (y - vmem) / 1.5f;
          unsigned short s = 0;
          if (vmem - 1.0f >= 0.f) { s = 0x3F80; vmem = 0.f; }
          sp[t][r] = s;
        }
      }
#pragma unroll
      for (int t = 0; t < NT; t++) {
        us4 pk;
#pragma unroll
        for (int r = 0; r < 4; r++) pk[r] = sp[t][r];
        *(us4*)&So[(size_t)(t * NN + n) * NC + ob] = pk;
      }
    }
  }
}

// ---------------------------------------------------------------------------
// Partial Gram: Mpart[ch][bh][e][dd] = sum_{l in 256-chunk} K[l][e]*V[l][dd].
__global__ void k_kvM(const unsigned short* __restrict__ STk,
                      const unsigned short* __restrict__ STv,
                      float* __restrict__ Mpart) {
  int bh = blockIdx.x, ch = blockIdx.y;
  int b = bh >> 3, h = bh & 7;
  const unsigned short* Kp = STk + (size_t)b * NL * NC + h * ND;
  const unsigned short* Vp = STv + (size_t)b * NL * NC + h * ND;
  __shared__ float sK[64][72];
  __shared__ float sV[64][72];
  int tid = threadIdx.x, tx = tid & 15, ty = tid >> 4;
  float acc[4][4] = {};
  for (int lt = 0; lt < 4; lt++) {
    int lb = ch * 256 + lt * 64;
#pragma unroll
    for (int i = 0; i < 2; i++) {
      int idx = tid + i * 256;
      int r = idx >> 3, seg = idx & 7;
      us8 kv = *(const us8*)&Kp[(size_t)(lb + r) * NC + seg * 8];
      us8 vv = *(const us8*)&Vp[(size_t)(lb + r) * NC + seg * 8];
#pragma unroll
      for (int q2 = 0; q2 < 8; q2++) {
        sK[r][seg * 8 + q2] = bu2f(kv[q2]);
        sV[r][seg * 8 + q2] = bu2f(vv[q2]);
      }
    }
    __syncthreads();
#pragma unroll 8
    for (int lc = 0; lc < 64; lc++) {
      float kvx[4], vvx[4];
#pragma unroll
      for (int i = 0; i < 4; i++) kvx[i] = sK[lc][ty * 4 + i];
#pragma unroll
      for (int j2 = 0; j2 < 4; j2++) vvx[j2] = sV[lc][tx * 4 + j2];
#pragma unroll
      for (int i = 0; i < 4; i++)
#pragma unroll
        for (int j2 = 0; j2 < 4; j2++)
          acc[i][j2] += kvx[i] * vvx[j2];
    }
    __syncthreads();
  }
  float* Mp = Mpart + ((size_t)ch * 64 + bh) * 4096;
#pragma unroll
  for (int i = 0; i < 4; i++) {
    float4 v4 = make_float4(acc[i][0], acc[i][1], acc[i][2], acc[i][3]);
    *(float4*)&Mp[(ty * 4 + i) * ND + tx * 4] = v4;
  }
}

// ---------------------------------------------------------------------------
// O[l][dd] = sum_e Q[l][e]*M[e][dd]; spike = (O >= 12). STs[b][l][c] bf16.
__global__ void k_attn(const unsigned short* __restrict__ STq,
                       const float* __restrict__ Mpart,
                       unsigned short* __restrict__ STs) {
  int lt = blockIdx.x, bh = blockIdx.y;
  int b = bh >> 3, h = bh & 7;
  __shared__ float sM[64][64];
  __shared__ float sQT[64][65];
  int tid = threadIdx.x, tx = tid & 15, ty = tid >> 4;
#pragma unroll
  for (int i = 0; i < 16; i++) {
    int idx = tid + i * 256;
    float s = 0.f;
#pragma unroll
    for (int ch = 0; ch < 4; ch++)
      s += Mpart[((size_t)ch * 64 + bh) * 4096 + idx];
    ((float*)sM)[idx] = s;
  }
  const unsigned short* Qp = STq + (size_t)b * NL * NC + h * ND;
#pragma unroll
  for (int i = 0; i < 2; i++) {
    int idx = tid + i * 256;
    int r = idx >> 3, seg = idx & 7;
    us8 qv = *(const us8*)&Qp[(size_t)(lt * 64 + r) * NC + seg * 8];
#pragma unroll
    for (int e2 = 0; e2 < 8; e2++) sQT[seg * 8 + e2][r] = bu2f(qv[e2]);
  }
  __syncthreads();
  float acc[4][4] = {};
#pragma unroll 8
  for (int e = 0; e < 64; e++) {
    float q[4], m[4];
#pragma unroll
    for (int i = 0; i < 4; i++) q[i] = sQT[e][ty * 4 + i];
#pragma unroll
    for (int j2 = 0; j2 < 4; j2++) m[j2] = sM[e][tx * 4 + j2];
#pragma unroll
    for (int i = 0; i < 4; i++)
#pragma unroll
      for (int j2 = 0; j2 < 4; j2++)
        acc[i][j2] += q[i] * m[j2];
  }
  unsigned short* Sp = STs + (size_t)b * NL * NC + h * ND;
#pragma unroll
  for (int i = 0; i < 4; i++) {
    us4 pk;
#pragma unroll
    for (int j2 = 0; j2 < 4; j2++) pk[j2] = (acc[i][j2] >= 12.0f) ? 0x3F80 : 0;
    *(us4*)&Sp[(size_t)(lt * 64 + ty * 4 + i) * NC + tx * 4] = pk;
  }
}

// ---------------------------------------------------------------------------
// Final projection: out[b][o][l] = sum_j Wp_j @ STs + bp. Tile 128 rows x
// 64 cols, grid 512 (2/CU). Same A-direct + B-dbuf structure as k_qkv.
__global__ __launch_bounds__(256) void
k_out(const unsigned short* __restrict__ H2,
      const unsigned short* __restrict__ STs,
      const float* __restrict__ bp, float* __restrict__ out) {
  __shared__ __align__(16) unsigned short sB[2][64 * 64];

  int id = blockIdx.x;                  // 512 = 16 l0 * 4 rt * 8 b
  int l0 = (id & 15) * 64;
  int rt = (id >> 4) & 3;
  int b  = id >> 6;

  int tid = threadIdx.x;
  int w = tid >> 6, lane = tid & 63, quad = lane >> 4, l15 = lane & 15;
  int xorv = l15 & 7;

  const unsigned short* Sb = STs + (size_t)b * NL * NC;

  f32x4 acc[2][4];
#pragma unroll
  for (int ri = 0; ri < 2; ri++)
#pragma unroll
    for (int jj = 0; jj < 4; jj++) acc[ri][jj] = (f32x4){0.f, 0.f, 0.f, 0.f};

  us8 breg[2];
  int ccs[2], segs[2];
  size_t bsrc[2];
#pragma unroll
  for (int i = 0; i < 2; i++) {
    int idx = tid + i * 256;
    int cc = idx >> 3, seg = idx & 7;
    ccs[i] = cc; segs[i] = seg;
    bsrc[i] = (size_t)(l0 + cc) * NC + seg * 8;
  }
#pragma unroll
  for (int i = 0; i < 2; i++) breg[i] = *(const us8*)&Sb[bsrc[i]];
#pragma unroll
  for (int i = 0; i < 2; i++)
    *(us8*)&sB[0][ccs[i] * 64 + ((segs[i] ^ (ccs[i] & 7)) << 3)] = breg[i];

  for (int k0i = 0; k0i < 8; k0i++) {
    __syncthreads();
    int buf = k0i & 1;
    if (k0i < 7) {
#pragma unroll
      for (int i = 0; i < 2; i++)
        breg[i] = *(const us8*)&Sb[bsrc[i] + (size_t)(k0i + 1) * 64];
    }
#pragma unroll
    for (int j = 0; j < 3; j++) {
      const unsigned short* Hj =
          H2 + ((size_t)(((9 + j) * 4 + rt) * 8 + k0i)) * 8192;   // p=3
#pragma unroll
      for (int ks = 0; ks < 2; ks++) {
        int c8 = ks * 4 + quad;
        short8v a0 = *(const short8v*)&Hj[(size_t)c8 * 1024 + (w * 32 + l15) * 8];
        short8v a1 = *(const short8v*)&Hj[(size_t)c8 * 1024 + (w * 32 + 16 + l15) * 8];
        int poff = (c8 ^ xorv) << 3;
#pragma unroll
        for (int jj = 0; jj < 4; jj++) {
          short8v bf = *(const short8v*)&sB[buf][(jj * 16 + l15) * 64 + poff];
          acc[0][jj] = __builtin_amdgcn_mfma_f32_16x16x32_bf16(a0, bf, acc[0][jj], 0, 0, 0);
          acc[1][jj] = __builtin_amdgcn_mfma_f32_16x16x32_bf16(a1, bf, acc[1][jj], 0, 0, 0);
        }
      }
    }
    if (k0i < 7) {
#pragma unroll
      for (int i = 0; i < 2; i++)
        *(us8*)&sB[buf ^ 1][ccs[i] * 64 + ((segs[i] ^ (ccs[i] & 7)) << 3)] = breg[i];
    }
  }

#pragma unroll
  for (int ri = 0; ri < 2; ri++) {
    int ob = rt * 128 + w * 32 + ri * 16 + quad * 4;
#pragma unroll
    for (int jj = 0; jj < 4; jj++) {
      int l = l0 + jj * 16 + l15;
#pragma unroll
      for (int r = 0; r < 4; r++)
        out[((size_t)(b * NC + ob + r)) * NL + l] = acc[ri][jj][r] + bp[ob + r];
    }
  }
}

// ---------------------------------------------------------------------------
extern "C" void kernel_launch(void* const* d_in, const int* in_sizes, int n_in,
                              void* d_out, int out_size, void* d_ws, size_t ws_size,
                              hipStream_t stream) {
  (void)in_sizes; (void)n_in; (void)out_size; (void)ws_size;
  const float* x   = (const float*)d_in[0];
  const float* wq  = (const float*)d_in[1];
  const float* wk  = (const float*)d_in[2];
  const float* wv  = (const float*)d_in[3];
  const float* wp  = (const float*)d_in[4];
  const float* bp  = (const float*)d_in[5];
  const float* gq  = (const float*)d_in[6];
  const float* bq  = (const float*)d_in[7];
  const float* mq  = (const float*)d_in[8];
  const float* vq  = (const float*)d_in[9];
  const float* gk  = (const float*)d_in[10];
  const float* bk  = (const float*)d_in[11];
  const float* mk  = (const float*)d_in[12];
  const float* vk  = (const float*)d_in[13];
  const float* gv  = (const float*)d_in[14];
  const float* bv  = (const float*)d_in[15];
  const float* mv  = (const float*)d_in[16];
  const float* vvv = (const float*)d_in[17];
  const float* gp  = (const float*)d_in[18];
  const float* bpn = (const float*)d_in[19];
  const float* mp  = (const float*)d_in[20];
  const float* vp  = (const float*)d_in[21];

  unsigned short* H2  = (unsigned short*)d_ws;
  unsigned short* ST0 = H2 + (size_t)4 * 3 * NC * NC;
  unsigned short* STq = ST0 + BCL;
  unsigned short* STk = STq + BCL;
  unsigned short* STv = STk + BCL;
  unsigned short* STs = STv + BCL;
  float* Mpart = (float*)(STs + BCL);

  dim3 blk(256);
  k_prep<<<1024, blk, 0, stream>>>(wq, wk, wv, wp, x, gp, bpn, mp, vp, H2, ST0);
  k_qkv<<<768, blk, 0, stream>>>(H2, ST0,
      gq, bq, mq, vq, gk, bk, mk, vk, gv, bv, mv, vvv, STq, STk, STv);
  k_kvM<<<dim3(64, 4), blk, 0, stream>>>(STk, STv, Mpart);
  k_attn<<<dim3(16, 64), blk, 0, stream>>>(STq, Mpart, STs);
  k_out<<<512, blk, 0, stream>>>(H2, STs, bp, (float*)d_out);
}

// Round 7
// 198.463 us; speedup vs baseline: 2.3034x; 1.0763x over previous
//
#include <hip/hip_runtime.h>
#include <hip/hip_bf16.h>

// SpikingSelfAttention — round 7: register-cached B fragments (1x LDS read per
// frag per k0, reused across 3 planes), batched A-loads from fragment-ordered
// weights, 1 barrier/k0. B=8, C=512, T=4, N=256, L=1024, H=8, d=64.
// Exact 3-way bf16 weight split; binary spikes; o = q @ (k^T v) integer-exact.

#define NB 8
#define NC 512
#define NT 4
#define NN 256
#define NL 1024
#define NH 8
#define ND 64
#define BCL (NB*NC*NL)

typedef __attribute__((ext_vector_type(8))) short  short8v;
typedef __attribute__((ext_vector_type(8))) unsigned short us8;
typedef __attribute__((ext_vector_type(4))) unsigned short us4;
typedef __attribute__((ext_vector_type(4))) float f32x4;

__device__ __forceinline__ float bu2f(unsigned short u) {
  return __uint_as_float(((unsigned)u) << 16);
}
__device__ __forceinline__ unsigned short f2bu(float f) {   // RNE f32->bf16
  unsigned b = __float_as_uint(f);
  return (unsigned short)((b + 0x7FFFu + ((b >> 16) & 1u)) >> 16);
}

// ---------------------------------------------------------------------------
// k_prep: blocks [0,512) = weight split into fragment-ordered H2;
//         blocks [512,1024) = proj BN+LIF -> ST0[b][l][c] bf16.
// H2 layout: offset = ((((p*3+j)*4+rt)*8+k0i)*8+chunk)*1024 + r*8
__global__ void k_prep(const float* __restrict__ wq, const float* __restrict__ wk,
                       const float* __restrict__ wv, const float* __restrict__ wp,
                       const float* __restrict__ x,
                       const float* __restrict__ g,  const float* __restrict__ bt,
                       const float* __restrict__ mu, const float* __restrict__ var,
                       unsigned short* __restrict__ H2,
                       unsigned short* __restrict__ ST0) {
  if (blockIdx.x < 512) {
    int gi = blockIdx.x * 256 + threadIdx.x;       // (p,o,k8): 4*512*64
    int p = gi >> 15;
    int o = (gi >> 6) & 511;
    int k8 = gi & 63;
    int rt = o >> 7, r = o & 127;
    int k0i = k8 >> 3, chunk = k8 & 7;
    const float* W = (p == 0) ? wq : (p == 1) ? wk : (p == 2) ? wv : wp;
    const float* src = W + (size_t)o * NC + k8 * 8;
    us8 a[3];
#pragma unroll
    for (int i = 0; i < 8; i++) {
      float w = src[i];
      unsigned short u1 = f2bu(w);
      float r1 = w - bu2f(u1);
      unsigned short u2 = f2bu(r1);
      float r2 = r1 - bu2f(u2);
      unsigned short u3 = f2bu(r2);
      a[0][i] = u1; a[1][i] = u2; a[2][i] = u3;
    }
#pragma unroll
    for (int j = 0; j < 3; j++) {
      size_t off = ((size_t)((((p * 3 + j) * 4 + rt) * 8 + k0i) * 8 + chunk)) * 1024
                   + (size_t)r * 8;
      *(us8*)&H2[off] = a[j];
    }
  } else {
    int bidx = blockIdx.x - 512;
    int b  = bidx >> 6;
    int c0 = (bidx & 63) * 8;
    int n  = threadIdx.x;
    unsigned short spk[NT][8];
#pragma unroll
    for (int i = 0; i < 8; i++) {
      int c = c0 + i;
      float inv = g[c] / sqrtf(var[c] + 1e-5f);
      float m = mu[c], be = bt[c];
      const float* xp = x + ((size_t)(b * NC + c)) * NL + n;
      float v = 0.f;
#pragma unroll
      for (int t = 0; t < NT; t++) {
        float y = (xp[t * NN] - m) * inv + be;
        v = v + (y - v) / 1.5f;
        unsigned short s = 0;
        if (v - 1.0f >= 0.f) { s = 0x3F80; v = 0.f; }
        spk[t][i] = s;
      }
    }
#pragma unroll
    for (int t = 0; t < NT; t++) {
      us8 pk;
#pragma unroll
      for (int i = 0; i < 8; i++) pk[i] = spk[t][i];
      *(us8*)&ST0[((size_t)b * NL + t * NN + n) * NC + c0] = pk;
    }
  }
}

// ---------------------------------------------------------------------------
// Fused q/k/v projection + BN + LIF. Tile 128 rows x 128 cols; 4 waves as
// 4x1 strips (32 rows x 128 cols). Per k0: B frags read ONCE from LDS into
// VGPRs and reused across the 3 weight planes; A frags direct from H2 (L2).
// Column order: cc = (n&15) + 16*t + 64*(n>>4); LIF over t in-lane (jj&3).
__global__ __launch_bounds__(256) void
k_qkv(const unsigned short* __restrict__ H2,
      const unsigned short* __restrict__ ST0,
      const float* __restrict__ gq, const float* __restrict__ bq,
      const float* __restrict__ mq, const float* __restrict__ vq,
      const float* __restrict__ gk, const float* __restrict__ bk,
      const float* __restrict__ mk, const float* __restrict__ vk,
      const float* __restrict__ gv, const float* __restrict__ bv,
      const float* __restrict__ mv, const float* __restrict__ vv,
      unsigned short* __restrict__ STq, unsigned short* __restrict__ STk,
      unsigned short* __restrict__ STv) {
  __shared__ __align__(16) unsigned short sB[2][128 * 64];

  int id = blockIdx.x;                  // 768 = 8 n0 * 4 rt * 8 b * 3 p
  int n0 = (id & 7) * 32;
  int rt = (id >> 3) & 3;
  int b  = (id >> 5) & 7;
  int p  = id >> 8;

  int tid = threadIdx.x;
  int w = tid >> 6, lane = tid & 63, quad = lane >> 4, l15 = lane & 15;
  int xorv = l15 & 7;

  const unsigned short* Sb = ST0 + (size_t)b * NL * NC;

  f32x4 acc[2][8];
#pragma unroll
  for (int ri = 0; ri < 2; ri++)
#pragma unroll
    for (int jj = 0; jj < 8; jj++) acc[ri][jj] = (f32x4){0.f, 0.f, 0.f, 0.f};

  // B-tile staging indices: thread's i-th us8: cc = idx>>3, seg = idx&7.
  us8 breg[4];
  int ccs[4], segs[4];
  size_t bsrc[4];
#pragma unroll
  for (int i = 0; i < 4; i++) {
    int idx = tid + i * 256;
    int cc = idx >> 3, seg = idx & 7;
    int t = (cc >> 4) & 3, nn = (cc & 15) | ((cc >> 6) << 4);
    ccs[i] = cc; segs[i] = seg;
    bsrc[i] = (size_t)(t * NN + n0 + nn) * NC + seg * 8;
  }
#pragma unroll
  for (int i = 0; i < 4; i++) breg[i] = *(const us8*)&Sb[bsrc[i]];      // k0=0
#pragma unroll
  for (int i = 0; i < 4; i++)
    *(us8*)&sB[0][ccs[i] * 64 + ((segs[i] ^ (ccs[i] & 7)) << 3)] = breg[i];

  for (int k0i = 0; k0i < 8; k0i++) {
    __syncthreads();                    // sB[buf] ready; buf^1 free to write
    int buf = k0i & 1;
    if (k0i < 7) {
#pragma unroll
      for (int i = 0; i < 4; i++)
        breg[i] = *(const us8*)&Sb[bsrc[i] + (size_t)(k0i + 1) * 64];
    }
#pragma unroll
    for (int ks = 0; ks < 2; ks++) {
      int c8 = ks * 4 + quad;
      int poff = (c8 ^ xorv) << 3;
      short8v bf[8];                    // B frags: read once, reuse over 3 planes
#pragma unroll
      for (int jj = 0; jj < 8; jj++)
        bf[jj] = *(const short8v*)&sB[buf][(jj * 16 + l15) * 64 + poff];
#pragma unroll
      for (int j = 0; j < 3; j++) {
        const unsigned short* Hj =
            H2 + ((size_t)(((p * 3 + j) * 4 + rt) * 8 + k0i)) * 8192
               + (size_t)c8 * 1024;
        short8v a0 = *(const short8v*)&Hj[(w * 32 + l15) * 8];
        short8v a1 = *(const short8v*)&Hj[(w * 32 + 16 + l15) * 8];
#pragma unroll
        for (int jj = 0; jj < 8; jj++) {
          acc[0][jj] = __builtin_amdgcn_mfma_f32_16x16x32_bf16(a0, bf[jj], acc[0][jj], 0, 0, 0);
          acc[1][jj] = __builtin_amdgcn_mfma_f32_16x16x32_bf16(a1, bf[jj], acc[1][jj], 0, 0, 0);
        }
      }
    }
    if (k0i < 7) {
#pragma unroll
      for (int i = 0; i < 4; i++)
        *(us8*)&sB[buf ^ 1][ccs[i] * 64 + ((segs[i] ^ (ccs[i] & 7)) << 3)] = breg[i];
    }
  }

  // Epilogue: BN + LIF over t (in-lane, jj = nh*4 + t).
  const float *g, *bb, *mm, *vr;
  unsigned short* So;
  if (p == 0)      { g = gq; bb = bq; mm = mq; vr = vq; So = STq; }
  else if (p == 1) { g = gk; bb = bk; mm = mk; vr = vk; So = STk; }
  else             { g = gv; bb = bv; mm = mv; vr = vv; So = STv; }
  So += (size_t)b * NL * NC;

#pragma unroll
  for (int ri = 0; ri < 2; ri++) {
    int ob = rt * 128 + w * 32 + ri * 16 + quad * 4;
    float av[4], mvv[4], bvv[4];
#pragma unroll
    for (int r = 0; r < 4; r++) {
      av[r]  = g[ob + r] / sqrtf(vr[ob + r] + 1e-5f);
      mvv[r] = mm[ob + r];
      bvv[r] = bb[ob + r];
    }
#pragma unroll
    for (int nh = 0; nh < 2; nh++) {
      int n = n0 + (nh << 4) + l15;
      unsigned short sp[4][4];          // [t][r]
#pragma unroll
      for (int r = 0; r < 4; r++) {
        float vmem = 0.f;
#pragma unroll
        for (int t = 0; t < NT; t++) {
          float y = (acc[ri][nh * 4 + t][r] - mvv[r]) * av[r] + bvv[r];
          vmem = vmem + (y - vmem) / 1.5f;
          unsigned short s = 0;
          if (vmem - 1.0f >= 0.f) { s = 0x3F80; vmem = 0.f; }
          sp[t][r] = s;
        }
      }
#pragma unroll
      for (int t = 0; t < NT; t++) {
        us4 pk;
#pragma unroll
        for (int r = 0; r < 4; r++) pk[r] = sp[t][r];
        *(us4*)&So[(size_t)(t * NN + n) * NC + ob] = pk;
      }
    }
  }
}

// ---------------------------------------------------------------------------
// Partial Gram: Mpart[ch][bh][e][dd] = sum_{l in 256-chunk} K[l][e]*V[l][dd].
__global__ void k_kvM(const unsigned short* __restrict__ STk,
                      const unsigned short* __restrict__ STv,
                      float* __restrict__ Mpart) {
  int bh = blockIdx.x, ch = blockIdx.y;
  int b = bh >> 3, h = bh & 7;
  const unsigned short* Kp = STk + (size_t)b * NL * NC + h * ND;
  const unsigned short* Vp = STv + (size_t)b * NL * NC + h * ND;
  __shared__ float sK[64][72];
  __shared__ float sV[64][72];
  int tid = threadIdx.x, tx = tid & 15, ty = tid >> 4;
  float acc[4][4] = {};
  for (int lt = 0; lt < 4; lt++) {
    int lb = ch * 256 + lt * 64;
#pragma unroll
    for (int i = 0; i < 2; i++) {
      int idx = tid + i * 256;
      int r = idx >> 3, seg = idx & 7;
      us8 kv = *(const us8*)&Kp[(size_t)(lb + r) * NC + seg * 8];
      us8 vv = *(const us8*)&Vp[(size_t)(lb + r) * NC + seg * 8];
#pragma unroll
      for (int q2 = 0; q2 < 8; q2++) {
        sK[r][seg * 8 + q2] = bu2f(kv[q2]);
        sV[r][seg * 8 + q2] = bu2f(vv[q2]);
      }
    }
    __syncthreads();
#pragma unroll 8
    for (int lc = 0; lc < 64; lc++) {
      float kvx[4], vvx[4];
#pragma unroll
      for (int i = 0; i < 4; i++) kvx[i] = sK[lc][ty * 4 + i];
#pragma unroll
      for (int j2 = 0; j2 < 4; j2++) vvx[j2] = sV[lc][tx * 4 + j2];
#pragma unroll
      for (int i = 0; i < 4; i++)
#pragma unroll
        for (int j2 = 0; j2 < 4; j2++)
          acc[i][j2] += kvx[i] * vvx[j2];
    }
    __syncthreads();
  }
  float* Mp = Mpart + ((size_t)ch * 64 + bh) * 4096;
#pragma unroll
  for (int i = 0; i < 4; i++) {
    float4 v4 = make_float4(acc[i][0], acc[i][1], acc[i][2], acc[i][3]);
    *(float4*)&Mp[(ty * 4 + i) * ND + tx * 4] = v4;
  }
}

// ---------------------------------------------------------------------------
// O[l][dd] = sum_e Q[l][e]*M[e][dd]; spike = (O >= 12). STs[b][l][c] bf16.
__global__ void k_attn(const unsigned short* __restrict__ STq,
                       const float* __restrict__ Mpart,
                       unsigned short* __restrict__ STs) {
  int lt = blockIdx.x, bh = blockIdx.y;
  int b = bh >> 3, h = bh & 7;
  __shared__ float sM[64][64];
  __shared__ float sQT[64][65];
  int tid = threadIdx.x, tx = tid & 15, ty = tid >> 4;
#pragma unroll
  for (int i = 0; i < 16; i++) {
    int idx = tid + i * 256;
    float s = 0.f;
#pragma unroll
    for (int ch = 0; ch < 4; ch++)
      s += Mpart[((size_t)ch * 64 + bh) * 4096 + idx];
    ((float*)sM)[idx] = s;
  }
  const unsigned short* Qp = STq + (size_t)b * NL * NC + h * ND;
#pragma unroll
  for (int i = 0; i < 2; i++) {
    int idx = tid + i * 256;
    int r = idx >> 3, seg = idx & 7;
    us8 qv = *(const us8*)&Qp[(size_t)(lt * 64 + r) * NC + seg * 8];
#pragma unroll
    for (int e2 = 0; e2 < 8; e2++) sQT[seg * 8 + e2][r] = bu2f(qv[e2]);
  }
  __syncthreads();
  float acc[4][4] = {};
#pragma unroll 8
  for (int e = 0; e < 64; e++) {
    float q[4], m[4];
#pragma unroll
    for (int i = 0; i < 4; i++) q[i] = sQT[e][ty * 4 + i];
#pragma unroll
    for (int j2 = 0; j2 < 4; j2++) m[j2] = sM[e][tx * 4 + j2];
#pragma unroll
    for (int i = 0; i < 4; i++)
#pragma unroll
      for (int j2 = 0; j2 < 4; j2++)
        acc[i][j2] += q[i] * m[j2];
  }
  unsigned short* Sp = STs + (size_t)b * NL * NC + h * ND;
#pragma unroll
  for (int i = 0; i < 4; i++) {
    us4 pk;
#pragma unroll
    for (int j2 = 0; j2 < 4; j2++) pk[j2] = (acc[i][j2] >= 12.0f) ? 0x3F80 : 0;
    *(us4*)&Sp[(size_t)(lt * 64 + ty * 4 + i) * NC + tx * 4] = pk;
  }
}

// ---------------------------------------------------------------------------
// Final projection: out[b][o][l] = sum_j Wp_j @ STs + bp. Tile 128 rows x
// 64 cols, grid 512. Same register-cached B structure as k_qkv.
__global__ __launch_bounds__(256) void
k_out(const unsigned short* __restrict__ H2,
      const unsigned short* __restrict__ STs,
      const float* __restrict__ bp, float* __restrict__ out) {
  __shared__ __align__(16) unsigned short sB[2][64 * 64];

  int id = blockIdx.x;                  // 512 = 16 l0 * 4 rt * 8 b
  int l0 = (id & 15) * 64;
  int rt = (id >> 4) & 3;
  int b  = id >> 6;

  int tid = threadIdx.x;
  int w = tid >> 6, lane = tid & 63, quad = lane >> 4, l15 = lane & 15;
  int xorv = l15 & 7;

  const unsigned short* Sb = STs + (size_t)b * NL * NC;

  f32x4 acc[2][4];
#pragma unroll
  for (int ri = 0; ri < 2; ri++)
#pragma unroll
    for (int jj = 0; jj < 4; jj++) acc[ri][jj] = (f32x4){0.f, 0.f, 0.f, 0.f};

  us8 breg[2];
  int ccs[2], segs[2];
  size_t bsrc[2];
#pragma unroll
  for (int i = 0; i < 2; i++) {
    int idx = tid + i * 256;
    int cc = idx >> 3, seg = idx & 7;
    ccs[i] = cc; segs[i] = seg;
    bsrc[i] = (size_t)(l0 + cc) * NC + seg * 8;
  }
#pragma unroll
  for (int i = 0; i < 2; i++) breg[i] = *(const us8*)&Sb[bsrc[i]];
#pragma unroll
  for (int i = 0; i < 2; i++)
    *(us8*)&sB[0][ccs[i] * 64 + ((segs[i] ^ (ccs[i] & 7)) << 3)] = breg[i];

  for (int k0i = 0; k0i < 8; k0i++) {
    __syncthreads();
    int buf = k0i & 1;
    if (k0i < 7) {
#pragma unroll
      for (int i = 0; i < 2; i++)
        breg[i] = *(const us8*)&Sb[bsrc[i] + (size_t)(k0i + 1) * 64];
    }
#pragma unroll
    for (int ks = 0; ks < 2; ks++) {
      int c8 = ks * 4 + quad;
      int poff = (c8 ^ xorv) << 3;
      short8v bf[4];
#pragma unroll
      for (int jj = 0; jj < 4; jj++)
        bf[jj] = *(const short8v*)&sB[buf][(jj * 16 + l15) * 64 + poff];
#pragma unroll
      for (int j = 0; j < 3; j++) {
        const unsigned short* Hj =
            H2 + ((size_t)(((9 + j) * 4 + rt) * 8 + k0i)) * 8192   // p=3
               + (size_t)c8 * 1024;
        short8v a0 = *(const short8v*)&Hj[(w * 32 + l15) * 8];
        short8v a1 = *(const short8v*)&Hj[(w * 32 + 16 + l15) * 8];
#pragma unroll
        for (int jj = 0; jj < 4; jj++) {
          acc[0][jj] = __builtin_amdgcn_mfma_f32_16x16x32_bf16(a0, bf[jj], acc[0][jj], 0, 0, 0);
          acc[1][jj] = __builtin_amdgcn_mfma_f32_16x16x32_bf16(a1, bf[jj], acc[1][jj], 0, 0, 0);
        }
      }
    }
    if (k0i < 7) {
#pragma unroll
      for (int i = 0; i < 2; i++)
        *(us8*)&sB[buf ^ 1][ccs[i] * 64 + ((segs[i] ^ (ccs[i] & 7)) << 3)] = breg[i];
    }
  }

#pragma unroll
  for (int ri = 0; ri < 2; ri++) {
    int ob = rt * 128 + w * 32 + ri * 16 + quad * 4;
#pragma unroll
    for (int jj = 0; jj < 4; jj++) {
      int l = l0 + jj * 16 + l15;
#pragma unroll
      for (int r = 0; r < 4; r++)
        out[((size_t)(b * NC + ob + r)) * NL + l] = acc[ri][jj][r] + bp[ob + r];
    }
  }
}

// ---------------------------------------------------------------------------
extern "C" void kernel_launch(void* const* d_in, const int* in_sizes, int n_in,
                              void* d_out, int out_size, void* d_ws, size_t ws_size,
                              hipStream_t stream) {
  (void)in_sizes; (void)n_in; (void)out_size; (void)ws_size;
  const float* x   = (const float*)d_in[0];
  const float* wq  = (const float*)d_in[1];
  const float* wk  = (const float*)d_in[2];
  const float* wv  = (const float*)d_in[3];
  const float* wp  = (const float*)d_in[4];
  const float* bp  = (const float*)d_in[5];
  const float* gq  = (const float*)d_in[6];
  const float* bq  = (const float*)d_in[7];
  const float* mq  = (const float*)d_in[8];
  const float* vq  = (const float*)d_in[9];
  const float* gk  = (const float*)d_in[10];
  const float* bk  = (const float*)d_in[11];
  const float* mk  = (const float*)d_in[12];
  const float* vk  = (const float*)d_in[13];
  const float* gv  = (const float*)d_in[14];
  const float* bv  = (const float*)d_in[15];
  const float* mv  = (const float*)d_in[16];
  const float* vvv = (const float*)d_in[17];
  const float* gp  = (const float*)d_in[18];
  const float* bpn = (const float*)d_in[19];
  const float* mp  = (const float*)d_in[20];
  const float* vp  = (const float*)d_in[21];

  unsigned short* H2  = (unsigned short*)d_ws;
  unsigned short* ST0 = H2 + (size_t)4 * 3 * NC * NC;
  unsigned short* STq = ST0 + BCL;
  unsigned short* STk = STq + BCL;
  unsigned short* STv = STk + BCL;
  unsigned short* STs = STv + BCL;
  float* Mpart = (float*)(STs + BCL);

  dim3 blk(256);
  k_prep<<<1024, blk, 0, stream>>>(wq, wk, wv, wp, x, gp, bpn, mp, vp, H2, ST0);
  k_qkv<<<768, blk, 0, stream>>>(H2, ST0,
      gq, bq, mq, vq, gk, bk, mk, vk, gv, bv, mv, vvv, STq, STk, STv);
  k_kvM<<<dim3(64, 4), blk, 0, stream>>>(STk, STv, Mpart);
  k_attn<<<dim3(16, 64), blk, 0, stream>>>(STq, Mpart, STs);
  k_out<<<512, blk, 0, stream>>>(H2, STs, bp, (float*)d_out);
}